// Round 10
// baseline (379.926 us; speedup 1.0000x reference)
//
#include <hip/hip_runtime.h>
#include <cstdint>

#define F_IN  128
#define F_HID 16
#define F_OUT 138
#define NBUCK 512        // dst buckets
#define NPB_SHIFT 8
#define NPB 256          // nodes per bucket
#define NB  512          // edge slabs for binning passes
#define SLAB_CAP 12544   // >= ceil(E/NB) = 12500
#define STAGE_CAP 18432  // >= max bucket edges (~16.4k avg + slack)

// ---------------------------------------------------------------------------
// Inline edge_index dtype detection: int64 (LE, values < 2^31) -> every odd
// int32 word is zero. Returns 2 (int64 stride in words) or 1 (int32).
__device__ __forceinline__ int edge_mult(const int* __restrict__ idx) {
    int nz = 0;
#pragma unroll
    for (int i = 1; i < 64; i += 2) nz |= idx[i];
    return nz ? 1 : 2;
}

// Pass A: per-slab LDS histogram of dst-buckets (reads dst only).
__global__ void k_bincount(const int* __restrict__ idx,
                           unsigned* __restrict__ cnt, int E) {
    __shared__ unsigned hist[NBUCK];
    int tid = threadIdx.x;
    for (int i = tid; i < NBUCK; i += 256) hist[i] = 0;
    __syncthreads();
    const int mult = edge_mult(idx);
    int slab = (E + NB - 1) / NB;
    int start = blockIdx.x * slab, end = min(E, start + slab);
    if (mult == 2) {
        for (int e = start + tid; e < end; e += 256) {
            int d = ((const int2*)idx)[(size_t)E + e].x;
            atomicAdd(&hist[d >> NPB_SHIFT], 1u);
        }
    } else {
        for (int e = start + tid; e < end; e += 256) {
            int d = idx[(size_t)E + e];
            atomicAdd(&hist[d >> NPB_SHIFT], 1u);
        }
    }
    __syncthreads();
    for (int i = tid; i < NBUCK; i += 256) cnt[(size_t)i * NB + blockIdx.x] = hist[i];
}

// Scan step 1: one block per bucket; exclusive-scan its NB slab counts in
// place (pair-per-thread Hillis-Steele); emit bucket total.
__global__ void k_scanA(unsigned* __restrict__ cnt, unsigned* __restrict__ bucketTot) {
    __shared__ unsigned sh[256];
    int t = threadIdx.x;
    unsigned* row = cnt + (size_t)blockIdx.x * NB;
    unsigned e0 = row[2 * t], e1 = row[2 * t + 1];
    unsigned pair = e0 + e1;
    sh[t] = pair;
    __syncthreads();
    for (int off = 1; off < 256; off <<= 1) {
        unsigned v = (t >= off) ? sh[t - off] : 0u;
        __syncthreads();
        sh[t] += v;
        __syncthreads();
    }
    unsigned excl = sh[t] - pair;
    row[2 * t] = excl;
    row[2 * t + 1] = excl + e0;
    if (t == 255) bucketTot[blockIdx.x] = sh[255];
}

// Scan step 2: one block (512 threads); exclusive scan of bucket totals.
__global__ void k_scanB(const unsigned* __restrict__ bucketTot,
                        unsigned* __restrict__ bucketPtr) {
    __shared__ unsigned sh[NBUCK];
    int t = threadIdx.x;
    unsigned c = bucketTot[t];
    sh[t] = c;
    __syncthreads();
    for (int off = 1; off < NBUCK; off <<= 1) {
        unsigned v = (t >= off) ? sh[t - off] : 0u;
        __syncthreads();
        sh[t] += v;
        __syncthreads();
    }
    bucketPtr[t] = sh[t] - c;          // exclusive
    if (t == NBUCK - 1) bucketPtr[NBUCK] = sh[t];
}

// Pass B with LDS write-combining: histogram slab by bucket, scan, scatter
// the slab's edges into LDS staging sorted by bucket, then wave-cooperative
// chunked copy-out to each (slab,bucket) global segment.
// Packed entry: (dstLocal<<17) | src  (8+17 = 25 bits, src < 2^17).
__global__ void __launch_bounds__(256)
k_binfill(const int* __restrict__ idx,
          const unsigned* __restrict__ cnt,
          const unsigned* __restrict__ bucketPtr,
          unsigned* __restrict__ binned, int E) {
    __shared__ unsigned hist[NBUCK];
    __shared__ unsigned sofs[NBUCK];
    __shared__ unsigned scur[NBUCK];
    __shared__ unsigned sh[256];
    __shared__ unsigned stage[SLAB_CAP];   // 50 KB
    int tid = threadIdx.x;
    for (int i = tid; i < NBUCK; i += 256) hist[i] = 0;
    __syncthreads();
    const int mult = edge_mult(idx);
    int slab = (E + NB - 1) / NB;
    int start = blockIdx.x * slab, end = min(E, start + slab);
    // phase 1: histogram (dst only)
    if (mult == 2) {
        for (int e = start + tid; e < end; e += 256)
            atomicAdd(&hist[((const int2*)idx)[(size_t)E + e].x >> NPB_SHIFT], 1u);
    } else {
        for (int e = start + tid; e < end; e += 256)
            atomicAdd(&hist[idx[(size_t)E + e] >> NPB_SHIFT], 1u);
    }
    __syncthreads();
    // phase 2: exclusive scan of 512 counts (pair per thread)
    unsigned e0 = hist[2 * tid], e1 = hist[2 * tid + 1];
    unsigned pair = e0 + e1;
    sh[tid] = pair;
    __syncthreads();
    for (int off = 1; off < 256; off <<= 1) {
        unsigned v = (tid >= off) ? sh[tid - off] : 0u;
        __syncthreads();
        sh[tid] += v;
        __syncthreads();
    }
    unsigned excl = sh[tid] - pair;
    sofs[2 * tid] = excl;         scur[2 * tid] = excl;
    sofs[2 * tid + 1] = excl + e0; scur[2 * tid + 1] = excl + e0;
    __syncthreads();
    // phase 3: scatter slab edges into LDS staging sorted by bucket
    for (int e = start + tid; e < end; e += 256) {
        int s, d;
        if (mult == 2) { s = ((const int2*)idx)[e].x; d = ((const int2*)idx)[(size_t)E + e].x; }
        else           { s = idx[e];                  d = idx[(size_t)E + e]; }
        unsigned pos = atomicAdd(&scur[d >> NPB_SHIFT], 1u);
        stage[pos] = ((unsigned)(d & (NPB - 1)) << 17) | (unsigned)s;
    }
    __syncthreads();
    // phase 4: chunked copy-out, one wave per bucket segment
    int wid = tid >> 6, lane = tid & 63;
    for (int b = wid; b < NBUCK; b += 4) {
        unsigned s0 = sofs[b], len = scur[b] - s0;
        if (len == 0) continue;
        unsigned gbase = cnt[(size_t)b * NB + blockIdx.x] + bucketPtr[b];
        for (unsigned i = lane; i < len; i += 64)
            binned[gbase + i] = stage[s0 + i];
    }
}

// Fused per-bucket: slice-aware degree histogram -> scan -> p0/p1 + dinv,
// then sort the bucket's edges into LDS staging by (node, slice) and stream
// out col[] as one coalesced sequential copy (fallback: direct scatter).
__global__ void __launch_bounds__(512)
k_ptrfill(const unsigned* __restrict__ bucketPtr,
          const unsigned* __restrict__ binned,
          unsigned* __restrict__ p0, unsigned* __restrict__ p1,
          float* __restrict__ dinv, int* __restrict__ col,
          int n, int E, int s1) {
    __shared__ unsigned deg0[NPB], deg1[NPB];
    __shared__ unsigned cur0[NPB], cur1[NPB];
    __shared__ unsigned sh[NPB];
    __shared__ unsigned stage[STAGE_CAP];   // 72 KB
    int tid = threadIdx.x, bb = blockIdx.x;
    if (tid < NPB) { deg0[tid] = 0; deg1[tid] = 0; }
    __syncthreads();
    unsigned start = bucketPtr[bb], end = bucketPtr[bb + 1];
    unsigned cntE = end - start;
    for (unsigned i = start + tid; i < end; i += 512) {
        unsigned entry = binned[i];
        int dl = (int)(entry >> 17);
        int src = (int)(entry & 0x1FFFFu);
        atomicAdd(src >= s1 ? &deg1[dl] : &deg0[dl], 1u);
    }
    __syncthreads();
    unsigned d0 = 0, d1 = 0, tot = 0;
    if (tid < NPB) { d0 = deg0[tid]; d1 = deg1[tid]; tot = d0 + d1; sh[tid] = tot; }
    __syncthreads();
    for (int off = 1; off < NPB; off <<= 1) {
        unsigned v = 0;
        if (tid < NPB && tid >= off) v = sh[tid - off];
        __syncthreads();
        if (tid < NPB) sh[tid] += v;
        __syncthreads();
    }
    if (tid < NPB) {
        unsigned lbase = sh[tid] - tot;       // exclusive prefix (local)
        cur0[tid] = lbase;
        cur1[tid] = lbase + d0;
        int v = (bb << NPB_SHIFT) + tid;
        if (v < n) {
            p0[v] = start + lbase;
            p1[v] = start + lbase + d0;
            dinv[v] = rsqrtf((float)(tot + 1u));   // +1 self-loop
        }
    }
    if (bb == 0 && tid == 0) p0[n] = (unsigned)E;
    __syncthreads();
    if (cntE <= STAGE_CAP) {
        for (unsigned i = start + tid; i < end; i += 512) {
            unsigned entry = binned[i];
            int dl = (int)(entry >> 17);
            unsigned src = entry & 0x1FFFFu;
            unsigned pos = atomicAdd((int)src >= s1 ? &cur1[dl] : &cur0[dl], 1u);
            stage[pos] = src;
        }
        __syncthreads();
        for (unsigned i = tid; i < cntE; i += 512)
            col[start + i] = (int)stage[i];
    } else {
        for (unsigned i = start + tid; i < end; i += 512) {
            unsigned entry = binned[i];
            int dl = (int)(entry >> 17);
            unsigned src = entry & 0x1FFFFu;
            unsigned pos = atomicAdd((int)src >= s1 ? &cur1[dl] : &cur0[dl], 1u);
            col[start + pos] = (int)src;
        }
    }
}

// g1[v][j] = dinv[v] * (x[v] . W1[:,j]).  16 nodes x 16 feats per block.
__global__ void k_gemm1(const float* __restrict__ x, const float* __restrict__ W1,
                        const float* __restrict__ dinv,
                        float* __restrict__ g1, int n) {
    __shared__ float w1s[F_IN * F_HID];     // 8 KB
    __shared__ float xs[16][F_IN + 4];
    int tid = threadIdx.x;
    for (int i = tid; i < F_IN * F_HID; i += 256) w1s[i] = W1[i];
    int nb = blockIdx.x * 16;
    for (int q = tid; q < 512; q += 256) {
        int r = q >> 5, k4 = q & 31;
        int g = nb + r;
        float4 v = make_float4(0.f, 0.f, 0.f, 0.f);
        if (g < n) v = ((const float4*)x)[(size_t)g * 32 + k4];
        xs[r][k4 * 4 + 0] = v.x; xs[r][k4 * 4 + 1] = v.y;
        xs[r][k4 * 4 + 2] = v.z; xs[r][k4 * 4 + 3] = v.w;
    }
    __syncthreads();
    int r = tid >> 4, j = tid & 15;
    int g = nb + r;
    if (g < n) {
        float acc = 0.f;
#pragma unroll
        for (int k = 0; k < F_IN; ++k) acc += xs[r][k] * w1s[k * F_HID + j];
        g1[(size_t)g * F_HID + j] = acc * dinv[g];
    }
}

// Pull-mode CSR aggregation over ONE src slice (full 16-wide rows, 16 lanes
// per node). Per pass all gathers hit a <=3.2 MB window of gin -> XCD-L2
// resident; col streamed NT; partial accumulator streamed NT.
template <int FIRST, int LAST, int RELU>
__global__ void __launch_bounds__(256)
k_agg(const unsigned* __restrict__ pA, const unsigned* __restrict__ pB,
      const int* __restrict__ col,
      const float* __restrict__ gin, float* __restrict__ acc_io,
      const float* __restrict__ dinv, const float* __restrict__ b1, int n) {
    int t = blockIdx.x * blockDim.x + threadIdx.x;
    int v = t >> 4, j = t & 15;
    if (v >= n) return;
    size_t o = (size_t)v * F_HID + j;
    float acc;
    if (FIRST) acc = gin[o];                               // self-loop
    else       acc = __builtin_nontemporal_load(acc_io + o);
    unsigned i = pA[v], end = pB[v];
    for (; i + 8 <= end; i += 8) {
        int u0 = __builtin_nontemporal_load(col + i);
        int u1 = __builtin_nontemporal_load(col + i + 1);
        int u2 = __builtin_nontemporal_load(col + i + 2);
        int u3 = __builtin_nontemporal_load(col + i + 3);
        int u4 = __builtin_nontemporal_load(col + i + 4);
        int u5 = __builtin_nontemporal_load(col + i + 5);
        int u6 = __builtin_nontemporal_load(col + i + 6);
        int u7 = __builtin_nontemporal_load(col + i + 7);
        float a0 = gin[(size_t)u0 * F_HID + j];
        float a1 = gin[(size_t)u1 * F_HID + j];
        float a2 = gin[(size_t)u2 * F_HID + j];
        float a3 = gin[(size_t)u3 * F_HID + j];
        float a4 = gin[(size_t)u4 * F_HID + j];
        float a5 = gin[(size_t)u5 * F_HID + j];
        float a6 = gin[(size_t)u6 * F_HID + j];
        float a7 = gin[(size_t)u7 * F_HID + j];
        acc += ((a0 + a1) + (a2 + a3)) + ((a4 + a5) + (a6 + a7));
    }
    for (; i < end; ++i)
        acc += gin[(size_t)__builtin_nontemporal_load(col + i) * F_HID + j];
    if (LAST) {
        float di = dinv[v];
        float r;
        if (RELU) r = fmaxf(di * acc + b1[j], 0.f) * di;
        else      r = di * acc;
        __builtin_nontemporal_store(r, acc_io + o);
    } else {
        __builtin_nontemporal_store(acc, acc_io + o);
    }
}

// out[v][c] = B[v] . W2[:,c] + b2[c]   (dinv already folded into B)
__global__ void k_out(const float* __restrict__ B,
                      const float* __restrict__ W2, const float* __restrict__ b2,
                      float* __restrict__ out, int n) {
    __shared__ float w2s[F_HID * F_OUT];
    __shared__ float b2s[F_OUT];
    int tid = threadIdx.x;
    for (int i = tid; i < F_HID * F_OUT; i += 256) w2s[i] = W2[i];
    if (tid < F_OUT) b2s[tid] = b2[tid];
    __syncthreads();
    int total = n * F_OUT;
    int stride = gridDim.x * blockDim.x;
    for (int i = blockIdx.x * blockDim.x + tid; i < total; i += stride) {
        int node = i / F_OUT, c = i - node * F_OUT;
        float acc = 0.f;
#pragma unroll
        for (int j = 0; j < F_HID; ++j) acc += B[(size_t)node * F_HID + j] * w2s[j * F_OUT + c];
        __builtin_nontemporal_store(acc + b2s[c], out + i);
    }
}

extern "C" void kernel_launch(void* const* d_in, const int* in_sizes, int n_in,
                              void* d_out, int out_size, void* d_ws, size_t ws_size,
                              hipStream_t stream) {
    const float* x   = (const float*)d_in[0];
    const int*   idx = (const int*)d_in[1];
    const float* W1  = (const float*)d_in[2];
    const float* b1  = (const float*)d_in[3];
    const float* W2  = (const float*)d_in[4];
    const float* b2  = (const float*)d_in[5];
    float* out = (float*)d_out;

    const int n = in_sizes[0] / F_IN;       // 100000
    const int E = in_sizes[1] / 2;          // 6400000
    const int s1 = (n + 1) / 2;             // src-slice boundary (3.2 MB halves)

    char* ws = (char*)d_ws;
    size_t off = 0;
    auto carve = [&](size_t bytes) { char* p = ws + off; off += (bytes + 255) / 256 * 256; return p; };
    float*    dinv      = (float*)carve((size_t)n * 4);
    unsigned* bucketPtr = (unsigned*)carve((NBUCK + 1) * 4);
    unsigned* bucketTot = (unsigned*)carve(NBUCK * 4);
    unsigned* cnt       = (unsigned*)carve((size_t)NBUCK * NB * 4);   // 1 MB
    unsigned* p0        = (unsigned*)carve(((size_t)n + 1) * 4);
    unsigned* p1        = (unsigned*)carve((size_t)n * 4);
    float*    bufA      = (float*)carve((size_t)n * F_HID * 4);       // 6.4 MB
    float*    bufB      = (float*)carve((size_t)n * F_HID * 4);       // 6.4 MB
    // binned (E words = 25.6 MB) and col (E words) live in d_out (55.2 MB);
    // both fully consumed before k_out overwrites d_out.
    unsigned* binned = (unsigned*)d_out;
    int*      col    = (int*)d_out + (size_t)E;

    const int B = 256;
    const int nbAgg = (n * F_HID + B - 1) / B;   // 6250
    k_bincount<<<NB, B, 0, stream>>>(idx, cnt, E);
    k_scanA   <<<NBUCK, B, 0, stream>>>(cnt, bucketTot);
    k_scanB   <<<1, NBUCK, 0, stream>>>(bucketTot, bucketPtr);
    k_binfill <<<NB, B, 0, stream>>>(idx, cnt, bucketPtr, binned, E);
    k_ptrfill <<<NBUCK, 512, 0, stream>>>(bucketPtr, binned, p0, p1, dinv, col, n, E, s1);
    k_gemm1   <<<(n + 15) / 16, B, 0, stream>>>(x, W1, dinv, bufA, n);
    // layer 1: slice-0 pass (partial), slice-1 pass (+relu epilogue)
    k_agg<1,0,0><<<nbAgg, B, 0, stream>>>(p0, p1,     col, bufA, bufB, dinv, b1, n);
    k_agg<0,1,1><<<nbAgg, B, 0, stream>>>(p1, p0 + 1, col, bufA, bufB, dinv, b1, n);
    // layer 2
    k_agg<1,0,0><<<nbAgg, B, 0, stream>>>(p0, p1,     col, bufB, bufA, dinv, b1, n);
    k_agg<0,1,0><<<nbAgg, B, 0, stream>>>(p1, p0 + 1, col, bufB, bufA, dinv, b1, n);
    k_out     <<<8192, B, 0, stream>>>(bufA, W2, b2, out, n);
}

// Round 11
// 313.608 us; speedup vs baseline: 1.2115x; 1.2115x over previous
//
#include <hip/hip_runtime.h>
#include <cstdint>

#define F_IN  128
#define F_HID 16
#define F_OUT 138
#define NBUCK 512        // dst buckets
#define NPB_SHIFT 8
#define NPB 256          // nodes per bucket
#define NB  512          // edge slabs for binning passes
#define SLAB_CAP 12544   // >= ceil(E/NB) = 12500
#define STAGE_CAP 18432  // >= max bucket edges (~16.4k avg + slack)

// ---------------------------------------------------------------------------
// Inline edge_index dtype detection: int64 (LE, values < 2^31) -> every odd
// int32 word is zero. Returns 2 (int64 stride in words) or 1 (int32).
__device__ __forceinline__ int edge_mult(const int* __restrict__ idx) {
    int nz = 0;
#pragma unroll
    for (int i = 1; i < 64; i += 2) nz |= idx[i];
    return nz ? 1 : 2;
}

// Pass A: per-slab LDS histogram of dst-buckets (reads dst only).
__global__ void __launch_bounds__(1024, 8)
k_bincount(const int* __restrict__ idx, unsigned* __restrict__ cnt, int E) {
    __shared__ unsigned hist[NBUCK];
    int tid = threadIdx.x;
    if (tid < NBUCK) hist[tid] = 0;
    __syncthreads();
    const int mult = edge_mult(idx);
    int slab = (E + NB - 1) / NB;
    int start = blockIdx.x * slab, end = min(E, start + slab);
    if (mult == 2) {
        for (int e = start + tid; e < end; e += 1024)
            atomicAdd(&hist[((const int2*)idx)[(size_t)E + e].x >> NPB_SHIFT], 1u);
    } else {
        for (int e = start + tid; e < end; e += 1024)
            atomicAdd(&hist[idx[(size_t)E + e] >> NPB_SHIFT], 1u);
    }
    __syncthreads();
    if (tid < NBUCK) cnt[(size_t)tid * NB + blockIdx.x] = hist[tid];
}

// Scan step 1: one block per bucket; exclusive-scan its NB slab counts in
// place (pair-per-thread Hillis-Steele); emit bucket total.
__global__ void k_scanA(unsigned* __restrict__ cnt, unsigned* __restrict__ bucketTot) {
    __shared__ unsigned sh[256];
    int t = threadIdx.x;
    unsigned* row = cnt + (size_t)blockIdx.x * NB;
    unsigned e0 = row[2 * t], e1 = row[2 * t + 1];
    unsigned pair = e0 + e1;
    sh[t] = pair;
    __syncthreads();
    for (int off = 1; off < 256; off <<= 1) {
        unsigned v = (t >= off) ? sh[t - off] : 0u;
        __syncthreads();
        sh[t] += v;
        __syncthreads();
    }
    unsigned excl = sh[t] - pair;
    row[2 * t] = excl;
    row[2 * t + 1] = excl + e0;
    if (t == 255) bucketTot[blockIdx.x] = sh[255];
}

// Scan step 2: one block (512 threads); exclusive scan of bucket totals.
__global__ void k_scanB(const unsigned* __restrict__ bucketTot,
                        unsigned* __restrict__ bucketPtr) {
    __shared__ unsigned sh[NBUCK];
    int t = threadIdx.x;
    unsigned c = bucketTot[t];
    sh[t] = c;
    __syncthreads();
    for (int off = 1; off < NBUCK; off <<= 1) {
        unsigned v = (t >= off) ? sh[t - off] : 0u;
        __syncthreads();
        sh[t] += v;
        __syncthreads();
    }
    bucketPtr[t] = sh[t] - c;          // exclusive
    if (t == NBUCK - 1) bucketPtr[NBUCK] = sh[t];
}

// Pass B with LDS write-combining, 1024 threads: histogram slab by bucket,
// scan, scatter the slab's edges into LDS staging sorted by bucket, then
// 16-lane-group copy-out to each (slab,bucket) global segment (~24 entries).
// Packed entry: (dstLocal<<17) | src  (8+17 = 25 bits, src < 2^17).
__global__ void __launch_bounds__(1024, 8)
k_binfill(const int* __restrict__ idx,
          const unsigned* __restrict__ cnt,
          const unsigned* __restrict__ bucketPtr,
          unsigned* __restrict__ binned, int E) {
    __shared__ unsigned hist[NBUCK];
    __shared__ unsigned sofs[NBUCK];
    __shared__ unsigned scur[NBUCK];
    __shared__ unsigned stage[SLAB_CAP];   // 50 KB
    int tid = threadIdx.x;
    if (tid < NBUCK) hist[tid] = 0;
    __syncthreads();
    const int mult = edge_mult(idx);
    int slab = (E + NB - 1) / NB;
    int start = blockIdx.x * slab, end = min(E, start + slab);
    // phase 1: histogram (dst only)
    if (mult == 2) {
        for (int e = start + tid; e < end; e += 1024)
            atomicAdd(&hist[((const int2*)idx)[(size_t)E + e].x >> NPB_SHIFT], 1u);
    } else {
        for (int e = start + tid; e < end; e += 1024)
            atomicAdd(&hist[idx[(size_t)E + e] >> NPB_SHIFT], 1u);
    }
    __syncthreads();
    // phase 2: exclusive scan of NBUCK counts (Hillis-Steele on tid<NBUCK)
    if (tid < NBUCK) scur[tid] = hist[tid];
    __syncthreads();
    for (int off = 1; off < NBUCK; off <<= 1) {
        unsigned v = 0;
        if (tid < NBUCK && tid >= off) v = scur[tid - off];
        __syncthreads();
        if (tid < NBUCK) scur[tid] += v;
        __syncthreads();
    }
    if (tid < NBUCK) {
        unsigned ex = scur[tid] - hist[tid];
        sofs[tid] = ex;
        scur[tid] = ex;
    }
    __syncthreads();
    // phase 3: scatter slab edges into LDS staging sorted by bucket
    for (int e = start + tid; e < end; e += 1024) {
        int s, d;
        if (mult == 2) { s = ((const int2*)idx)[e].x; d = ((const int2*)idx)[(size_t)E + e].x; }
        else           { s = idx[e];                  d = idx[(size_t)E + e]; }
        unsigned pos = atomicAdd(&scur[d >> NPB_SHIFT], 1u);
        stage[pos] = ((unsigned)(d & (NPB - 1)) << 17) | (unsigned)s;
    }
    __syncthreads();
    // phase 4: copy-out, one 16-lane group per bucket segment
    int g = tid >> 4, lane = tid & 15;       // 64 groups
    for (int b = g; b < NBUCK; b += 64) {
        unsigned s0 = sofs[b], len = scur[b] - s0;
        if (len == 0) continue;
        unsigned gbase = cnt[(size_t)b * NB + blockIdx.x] + bucketPtr[b];
        for (unsigned i = lane; i < len; i += 16)
            binned[gbase + i] = stage[s0 + i];
    }
}

// Fused per-bucket (1024 threads): slice-aware degree histogram -> scan ->
// p0/p1 + dinv, then sort the bucket's edges into LDS staging by (node,
// slice) and stream out col[] as one coalesced sequential copy.
__global__ void __launch_bounds__(1024, 8)
k_ptrfill(const unsigned* __restrict__ bucketPtr,
          const unsigned* __restrict__ binned,
          unsigned* __restrict__ p0, unsigned* __restrict__ p1,
          float* __restrict__ dinv, int* __restrict__ col,
          int n, int E, int s1) {
    __shared__ unsigned deg0[NPB], deg1[NPB];
    __shared__ unsigned cur0[NPB], cur1[NPB];
    __shared__ unsigned sh[NPB];
    __shared__ unsigned stage[STAGE_CAP];   // 72 KB
    int tid = threadIdx.x, bb = blockIdx.x;
    if (tid < NPB) { deg0[tid] = 0; deg1[tid] = 0; }
    __syncthreads();
    unsigned start = bucketPtr[bb], end = bucketPtr[bb + 1];
    unsigned cntE = end - start;
    for (unsigned i = start + tid; i < end; i += 1024) {
        unsigned entry = binned[i];
        int dl = (int)(entry >> 17);
        int src = (int)(entry & 0x1FFFFu);
        atomicAdd(src >= s1 ? &deg1[dl] : &deg0[dl], 1u);
    }
    __syncthreads();
    unsigned d0 = 0, d1 = 0, tot = 0;
    if (tid < NPB) { d0 = deg0[tid]; d1 = deg1[tid]; tot = d0 + d1; sh[tid] = tot; }
    __syncthreads();
    for (int off = 1; off < NPB; off <<= 1) {
        unsigned v = 0;
        if (tid < NPB && tid >= off) v = sh[tid - off];
        __syncthreads();
        if (tid < NPB) sh[tid] += v;
        __syncthreads();
    }
    if (tid < NPB) {
        unsigned lbase = sh[tid] - tot;       // exclusive prefix (local)
        cur0[tid] = lbase;
        cur1[tid] = lbase + d0;
        int v = (bb << NPB_SHIFT) + tid;
        if (v < n) {
            p0[v] = start + lbase;
            p1[v] = start + lbase + d0;
            dinv[v] = rsqrtf((float)(tot + 1u));   // +1 self-loop
        }
    }
    if (bb == 0 && tid == 0) p0[n] = (unsigned)E;
    __syncthreads();
    if (cntE <= STAGE_CAP) {
        for (unsigned i = start + tid; i < end; i += 1024) {
            unsigned entry = binned[i];
            int dl = (int)(entry >> 17);
            unsigned src = entry & 0x1FFFFu;
            unsigned pos = atomicAdd((int)src >= s1 ? &cur1[dl] : &cur0[dl], 1u);
            stage[pos] = src;
        }
        __syncthreads();
        for (unsigned i = tid; i < cntE; i += 1024)
            col[start + i] = (int)stage[i];
    } else {
        for (unsigned i = start + tid; i < end; i += 1024) {
            unsigned entry = binned[i];
            int dl = (int)(entry >> 17);
            unsigned src = entry & 0x1FFFFu;
            unsigned pos = atomicAdd((int)src >= s1 ? &cur1[dl] : &cur0[dl], 1u);
            col[start + pos] = (int)src;
        }
    }
}

// g1[v][j] = dinv[v] * (x[v] . W1[:,j]).  16 nodes x 16 feats per block.
__global__ void k_gemm1(const float* __restrict__ x, const float* __restrict__ W1,
                        const float* __restrict__ dinv,
                        float* __restrict__ g1, int n) {
    __shared__ float w1s[F_IN * F_HID];     // 8 KB
    __shared__ float xs[16][F_IN + 4];
    int tid = threadIdx.x;
    for (int i = tid; i < F_IN * F_HID; i += 256) w1s[i] = W1[i];
    int nb = blockIdx.x * 16;
    for (int q = tid; q < 512; q += 256) {
        int r = q >> 5, k4 = q & 31;
        int g = nb + r;
        float4 v = make_float4(0.f, 0.f, 0.f, 0.f);
        if (g < n) v = ((const float4*)x)[(size_t)g * 32 + k4];
        xs[r][k4 * 4 + 0] = v.x; xs[r][k4 * 4 + 1] = v.y;
        xs[r][k4 * 4 + 2] = v.z; xs[r][k4 * 4 + 3] = v.w;
    }
    __syncthreads();
    int r = tid >> 4, j = tid & 15;
    int g = nb + r;
    if (g < n) {
        float acc = 0.f;
#pragma unroll
        for (int k = 0; k < F_IN; ++k) acc += xs[r][k] * w1s[k * F_HID + j];
        g1[(size_t)g * F_HID + j] = acc * dinv[g];
    }
}

// Pull-mode CSR aggregation over ONE src slice (full 16-wide rows, 16 lanes
// per node). Per pass all gathers hit a <=3.2 MB window of gin -> XCD-L2
// resident; col streamed NT; partial accumulator streamed NT.
template <int FIRST, int LAST, int RELU>
__global__ void __launch_bounds__(256)
k_agg(const unsigned* __restrict__ pA, const unsigned* __restrict__ pB,
      const int* __restrict__ col,
      const float* __restrict__ gin, float* __restrict__ acc_io,
      const float* __restrict__ dinv, const float* __restrict__ b1, int n) {
    int t = blockIdx.x * blockDim.x + threadIdx.x;
    int v = t >> 4, j = t & 15;
    if (v >= n) return;
    size_t o = (size_t)v * F_HID + j;
    float acc;
    if (FIRST) acc = gin[o];                               // self-loop
    else       acc = __builtin_nontemporal_load(acc_io + o);
    unsigned i = pA[v], end = pB[v];
    for (; i + 8 <= end; i += 8) {
        int u0 = __builtin_nontemporal_load(col + i);
        int u1 = __builtin_nontemporal_load(col + i + 1);
        int u2 = __builtin_nontemporal_load(col + i + 2);
        int u3 = __builtin_nontemporal_load(col + i + 3);
        int u4 = __builtin_nontemporal_load(col + i + 4);
        int u5 = __builtin_nontemporal_load(col + i + 5);
        int u6 = __builtin_nontemporal_load(col + i + 6);
        int u7 = __builtin_nontemporal_load(col + i + 7);
        float a0 = gin[(size_t)u0 * F_HID + j];
        float a1 = gin[(size_t)u1 * F_HID + j];
        float a2 = gin[(size_t)u2 * F_HID + j];
        float a3 = gin[(size_t)u3 * F_HID + j];
        float a4 = gin[(size_t)u4 * F_HID + j];
        float a5 = gin[(size_t)u5 * F_HID + j];
        float a6 = gin[(size_t)u6 * F_HID + j];
        float a7 = gin[(size_t)u7 * F_HID + j];
        acc += ((a0 + a1) + (a2 + a3)) + ((a4 + a5) + (a6 + a7));
    }
    for (; i < end; ++i)
        acc += gin[(size_t)__builtin_nontemporal_load(col + i) * F_HID + j];
    if (LAST) {
        float di = dinv[v];
        float r;
        if (RELU) r = fmaxf(di * acc + b1[j], 0.f) * di;
        else      r = di * acc;
        __builtin_nontemporal_store(r, acc_io + o);
    } else {
        __builtin_nontemporal_store(acc, acc_io + o);
    }
}

// out[v][c] = B[v] . W2[:,c] + b2[c]   (dinv already folded into B)
__global__ void k_out(const float* __restrict__ B,
                      const float* __restrict__ W2, const float* __restrict__ b2,
                      float* __restrict__ out, int n) {
    __shared__ float w2s[F_HID * F_OUT];
    __shared__ float b2s[F_OUT];
    int tid = threadIdx.x;
    for (int i = tid; i < F_HID * F_OUT; i += 256) w2s[i] = W2[i];
    if (tid < F_OUT) b2s[tid] = b2[tid];
    __syncthreads();
    int total = n * F_OUT;
    int stride = gridDim.x * blockDim.x;
    for (int i = blockIdx.x * blockDim.x + tid; i < total; i += stride) {
        int node = i / F_OUT, c = i - node * F_OUT;
        float acc = 0.f;
#pragma unroll
        for (int j = 0; j < F_HID; ++j) acc += B[(size_t)node * F_HID + j] * w2s[j * F_OUT + c];
        __builtin_nontemporal_store(acc + b2s[c], out + i);
    }
}

extern "C" void kernel_launch(void* const* d_in, const int* in_sizes, int n_in,
                              void* d_out, int out_size, void* d_ws, size_t ws_size,
                              hipStream_t stream) {
    const float* x   = (const float*)d_in[0];
    const int*   idx = (const int*)d_in[1];
    const float* W1  = (const float*)d_in[2];
    const float* b1  = (const float*)d_in[3];
    const float* W2  = (const float*)d_in[4];
    const float* b2  = (const float*)d_in[5];
    float* out = (float*)d_out;

    const int n = in_sizes[0] / F_IN;       // 100000
    const int E = in_sizes[1] / 2;          // 6400000
    const int s1 = (n + 1) / 2;             // src-slice boundary (3.2 MB halves)

    char* ws = (char*)d_ws;
    size_t off = 0;
    auto carve = [&](size_t bytes) { char* p = ws + off; off += (bytes + 255) / 256 * 256; return p; };
    float*    dinv      = (float*)carve((size_t)n * 4);
    unsigned* bucketPtr = (unsigned*)carve((NBUCK + 1) * 4);
    unsigned* bucketTot = (unsigned*)carve(NBUCK * 4);
    unsigned* cnt       = (unsigned*)carve((size_t)NBUCK * NB * 4);   // 1 MB
    unsigned* p0        = (unsigned*)carve(((size_t)n + 1) * 4);
    unsigned* p1        = (unsigned*)carve((size_t)n * 4);
    float*    bufA      = (float*)carve((size_t)n * F_HID * 4);       // 6.4 MB
    float*    bufB      = (float*)carve((size_t)n * F_HID * 4);       // 6.4 MB
    // binned (E words = 25.6 MB) and col (E words) live in d_out (55.2 MB);
    // both fully consumed before k_out overwrites d_out.
    unsigned* binned = (unsigned*)d_out;
    int*      col    = (int*)d_out + (size_t)E;

    const int B = 256;
    const int nbAgg = (n * F_HID + B - 1) / B;   // 6250
    k_bincount<<<NB, 1024, 0, stream>>>(idx, cnt, E);
    k_scanA   <<<NBUCK, B, 0, stream>>>(cnt, bucketTot);
    k_scanB   <<<1, NBUCK, 0, stream>>>(bucketTot, bucketPtr);
    k_binfill <<<NB, 1024, 0, stream>>>(idx, cnt, bucketPtr, binned, E);
    k_ptrfill <<<NBUCK, 1024, 0, stream>>>(bucketPtr, binned, p0, p1, dinv, col, n, E, s1);
    k_gemm1   <<<(n + 15) / 16, B, 0, stream>>>(x, W1, dinv, bufA, n);
    // layer 1: slice-0 pass (partial), slice-1 pass (+relu epilogue)
    k_agg<1,0,0><<<nbAgg, B, 0, stream>>>(p0, p1,     col, bufA, bufB, dinv, b1, n);
    k_agg<0,1,1><<<nbAgg, B, 0, stream>>>(p1, p0 + 1, col, bufA, bufB, dinv, b1, n);
    // layer 2
    k_agg<1,0,0><<<nbAgg, B, 0, stream>>>(p0, p1,     col, bufB, bufA, dinv, b1, n);
    k_agg<0,1,0><<<nbAgg, B, 0, stream>>>(p1, p0 + 1, col, bufB, bufA, dinv, b1, n);
    k_out     <<<8192, B, 0, stream>>>(bufA, W2, b2, out, n);
}

// Round 12
// 300.449 us; speedup vs baseline: 1.2645x; 1.0438x over previous
//
#include <hip/hip_runtime.h>
#include <cstdint>

#define F_IN  128
#define F_HID 16
#define F_OUT 138
#define NBUCK 512        // dst buckets
#define NPB_SHIFT 8
#define NPB 256          // nodes per bucket
#define NB  512          // edge slabs for binning passes
#define SLAB_CAP 12544   // >= ceil(E/NB) = 12500
#define STAGE_CAP 18432  // >= max bucket edges (~16.4k avg + slack)
#define OUT_NV 16        // nodes per k_out block

// ---------------------------------------------------------------------------
// Inline edge_index dtype detection: int64 (LE, values < 2^31) -> every odd
// int32 word is zero. Returns 2 (int64 stride in words) or 1 (int32).
__device__ __forceinline__ int edge_mult(const int* __restrict__ idx) {
    int nz = 0;
#pragma unroll
    for (int i = 1; i < 64; i += 2) nz |= idx[i];
    return nz ? 1 : 2;
}

// Pass A: per-slab LDS histogram of dst-buckets (reads dst only).
__global__ void __launch_bounds__(1024, 8)
k_bincount(const int* __restrict__ idx, unsigned* __restrict__ cnt, int E) {
    __shared__ unsigned hist[NBUCK];
    int tid = threadIdx.x;
    if (tid < NBUCK) hist[tid] = 0;
    __syncthreads();
    const int mult = edge_mult(idx);
    int slab = (E + NB - 1) / NB;
    int start = blockIdx.x * slab, end = min(E, start + slab);
    if (mult == 2) {
        for (int e = start + tid; e < end; e += 1024)
            atomicAdd(&hist[((const int2*)idx)[(size_t)E + e].x >> NPB_SHIFT], 1u);
    } else {
        for (int e = start + tid; e < end; e += 1024)
            atomicAdd(&hist[idx[(size_t)E + e] >> NPB_SHIFT], 1u);
    }
    __syncthreads();
    if (tid < NBUCK) cnt[(size_t)tid * NB + blockIdx.x] = hist[tid];
}

// Scan step 1: one block per bucket; exclusive-scan its NB slab counts in
// place (pair-per-thread Hillis-Steele); emit bucket total.
__global__ void k_scanA(unsigned* __restrict__ cnt, unsigned* __restrict__ bucketTot) {
    __shared__ unsigned sh[256];
    int t = threadIdx.x;
    unsigned* row = cnt + (size_t)blockIdx.x * NB;
    unsigned e0 = row[2 * t], e1 = row[2 * t + 1];
    unsigned pair = e0 + e1;
    sh[t] = pair;
    __syncthreads();
    for (int off = 1; off < 256; off <<= 1) {
        unsigned v = (t >= off) ? sh[t - off] : 0u;
        __syncthreads();
        sh[t] += v;
        __syncthreads();
    }
    unsigned excl = sh[t] - pair;
    row[2 * t] = excl;
    row[2 * t + 1] = excl + e0;
    if (t == 255) bucketTot[blockIdx.x] = sh[255];
}

// Scan step 2: one block (512 threads); exclusive scan of bucket totals.
__global__ void k_scanB(const unsigned* __restrict__ bucketTot,
                        unsigned* __restrict__ bucketPtr) {
    __shared__ unsigned sh[NBUCK];
    int t = threadIdx.x;
    unsigned c = bucketTot[t];
    sh[t] = c;
    __syncthreads();
    for (int off = 1; off < NBUCK; off <<= 1) {
        unsigned v = (t >= off) ? sh[t - off] : 0u;
        __syncthreads();
        sh[t] += v;
        __syncthreads();
    }
    bucketPtr[t] = sh[t] - c;          // exclusive
    if (t == NBUCK - 1) bucketPtr[NBUCK] = sh[t];
}

// Pass B with LDS write-combining, 1024 threads: histogram slab by bucket,
// scan, scatter the slab's edges into LDS staging sorted by bucket, then
// 16-lane-group copy-out to each (slab,bucket) global segment (~24 entries).
// Packed entry: (dstLocal<<17) | src  (8+17 = 25 bits, src < 2^17).
__global__ void __launch_bounds__(1024, 8)
k_binfill(const int* __restrict__ idx,
          const unsigned* __restrict__ cnt,
          const unsigned* __restrict__ bucketPtr,
          unsigned* __restrict__ binned, int E) {
    __shared__ unsigned hist[NBUCK];
    __shared__ unsigned sofs[NBUCK];
    __shared__ unsigned scur[NBUCK];
    __shared__ unsigned stage[SLAB_CAP];   // 50 KB
    int tid = threadIdx.x;
    if (tid < NBUCK) hist[tid] = 0;
    __syncthreads();
    const int mult = edge_mult(idx);
    int slab = (E + NB - 1) / NB;
    int start = blockIdx.x * slab, end = min(E, start + slab);
    // phase 1: histogram (dst only)
    if (mult == 2) {
        for (int e = start + tid; e < end; e += 1024)
            atomicAdd(&hist[((const int2*)idx)[(size_t)E + e].x >> NPB_SHIFT], 1u);
    } else {
        for (int e = start + tid; e < end; e += 1024)
            atomicAdd(&hist[idx[(size_t)E + e] >> NPB_SHIFT], 1u);
    }
    __syncthreads();
    // phase 2: exclusive scan of NBUCK counts (Hillis-Steele on tid<NBUCK)
    if (tid < NBUCK) scur[tid] = hist[tid];
    __syncthreads();
    for (int off = 1; off < NBUCK; off <<= 1) {
        unsigned v = 0;
        if (tid < NBUCK && tid >= off) v = scur[tid - off];
        __syncthreads();
        if (tid < NBUCK) scur[tid] += v;
        __syncthreads();
    }
    if (tid < NBUCK) {
        unsigned ex = scur[tid] - hist[tid];
        sofs[tid] = ex;
        scur[tid] = ex;
    }
    __syncthreads();
    // phase 3: scatter slab edges into LDS staging sorted by bucket
    for (int e = start + tid; e < end; e += 1024) {
        int s, d;
        if (mult == 2) { s = ((const int2*)idx)[e].x; d = ((const int2*)idx)[(size_t)E + e].x; }
        else           { s = idx[e];                  d = idx[(size_t)E + e]; }
        unsigned pos = atomicAdd(&scur[d >> NPB_SHIFT], 1u);
        stage[pos] = ((unsigned)(d & (NPB - 1)) << 17) | (unsigned)s;
    }
    __syncthreads();
    // phase 4: copy-out, one 16-lane group per bucket segment
    int g = tid >> 4, lane = tid & 15;       // 64 groups
    for (int b = g; b < NBUCK; b += 64) {
        unsigned s0 = sofs[b], len = scur[b] - s0;
        if (len == 0) continue;
        unsigned gbase = cnt[(size_t)b * NB + blockIdx.x] + bucketPtr[b];
        for (unsigned i = lane; i < len; i += 16)
            binned[gbase + i] = stage[s0 + i];
    }
}

// Fused per-bucket (1024 threads): slice-aware degree histogram -> scan ->
// p0/p1 + dinv, then sort the bucket's edges into LDS staging by (node,
// slice) and stream out col[] as one coalesced sequential copy.
__global__ void __launch_bounds__(1024, 8)
k_ptrfill(const unsigned* __restrict__ bucketPtr,
          const unsigned* __restrict__ binned,
          unsigned* __restrict__ p0, unsigned* __restrict__ p1,
          float* __restrict__ dinv, int* __restrict__ col,
          int n, int E, int s1) {
    __shared__ unsigned deg0[NPB], deg1[NPB];
    __shared__ unsigned cur0[NPB], cur1[NPB];
    __shared__ unsigned sh[NPB];
    __shared__ unsigned stage[STAGE_CAP];   // 72 KB
    int tid = threadIdx.x, bb = blockIdx.x;
    if (tid < NPB) { deg0[tid] = 0; deg1[tid] = 0; }
    __syncthreads();
    unsigned start = bucketPtr[bb], end = bucketPtr[bb + 1];
    unsigned cntE = end - start;
    for (unsigned i = start + tid; i < end; i += 1024) {
        unsigned entry = binned[i];
        int dl = (int)(entry >> 17);
        int src = (int)(entry & 0x1FFFFu);
        atomicAdd(src >= s1 ? &deg1[dl] : &deg0[dl], 1u);
    }
    __syncthreads();
    unsigned d0 = 0, d1 = 0, tot = 0;
    if (tid < NPB) { d0 = deg0[tid]; d1 = deg1[tid]; tot = d0 + d1; sh[tid] = tot; }
    __syncthreads();
    for (int off = 1; off < NPB; off <<= 1) {
        unsigned v = 0;
        if (tid < NPB && tid >= off) v = sh[tid - off];
        __syncthreads();
        if (tid < NPB) sh[tid] += v;
        __syncthreads();
    }
    if (tid < NPB) {
        unsigned lbase = sh[tid] - tot;       // exclusive prefix (local)
        cur0[tid] = lbase;
        cur1[tid] = lbase + d0;
        int v = (bb << NPB_SHIFT) + tid;
        if (v < n) {
            p0[v] = start + lbase;
            p1[v] = start + lbase + d0;
            dinv[v] = rsqrtf((float)(tot + 1u));   // +1 self-loop
        }
    }
    if (bb == 0 && tid == 0) p0[n] = (unsigned)E;
    __syncthreads();
    if (cntE <= STAGE_CAP) {
        for (unsigned i = start + tid; i < end; i += 1024) {
            unsigned entry = binned[i];
            int dl = (int)(entry >> 17);
            unsigned src = entry & 0x1FFFFu;
            unsigned pos = atomicAdd((int)src >= s1 ? &cur1[dl] : &cur0[dl], 1u);
            stage[pos] = src;
        }
        __syncthreads();
        for (unsigned i = tid; i < cntE; i += 1024)
            col[start + i] = (int)stage[i];
    } else {
        for (unsigned i = start + tid; i < end; i += 1024) {
            unsigned entry = binned[i];
            int dl = (int)(entry >> 17);
            unsigned src = entry & 0x1FFFFu;
            unsigned pos = atomicAdd((int)src >= s1 ? &cur1[dl] : &cur0[dl], 1u);
            col[start + pos] = (int)src;
        }
    }
}

// g1[v][j] = dinv[v] * (x[v] . W1[:,j]).  16 nodes x 16 feats per block.
__global__ void k_gemm1(const float* __restrict__ x, const float* __restrict__ W1,
                        const float* __restrict__ dinv,
                        float* __restrict__ g1, int n) {
    __shared__ float w1s[F_IN * F_HID];     // 8 KB
    __shared__ float xs[16][F_IN + 4];
    int tid = threadIdx.x;
    for (int i = tid; i < F_IN * F_HID; i += 256) w1s[i] = W1[i];
    int nb = blockIdx.x * 16;
    for (int q = tid; q < 512; q += 256) {
        int r = q >> 5, k4 = q & 31;
        int g = nb + r;
        float4 v = make_float4(0.f, 0.f, 0.f, 0.f);
        if (g < n) v = ((const float4*)x)[(size_t)g * 32 + k4];
        xs[r][k4 * 4 + 0] = v.x; xs[r][k4 * 4 + 1] = v.y;
        xs[r][k4 * 4 + 2] = v.z; xs[r][k4 * 4 + 3] = v.w;
    }
    __syncthreads();
    int r = tid >> 4, j = tid & 15;
    int g = nb + r;
    if (g < n) {
        float acc = 0.f;
#pragma unroll
        for (int k = 0; k < F_IN; ++k) acc += xs[r][k] * w1s[k * F_HID + j];
        g1[(size_t)g * F_HID + j] = acc * dinv[g];
    }
}

// Pull-mode CSR aggregation over ONE src slice (full 16-wide rows, 16 lanes
// per node). Per pass all gathers hit a <=3.2 MB window of gin -> XCD-L2
// resident; col streamed NT; partial accumulator streamed NT.
template <int FIRST, int LAST, int RELU>
__global__ void __launch_bounds__(256)
k_agg(const unsigned* __restrict__ pA, const unsigned* __restrict__ pB,
      const int* __restrict__ col,
      const float* __restrict__ gin, float* __restrict__ acc_io,
      const float* __restrict__ dinv, const float* __restrict__ b1, int n) {
    int t = blockIdx.x * blockDim.x + threadIdx.x;
    int v = t >> 4, j = t & 15;
    if (v >= n) return;
    size_t o = (size_t)v * F_HID + j;
    float acc;
    if (FIRST) acc = gin[o];                               // self-loop
    else       acc = __builtin_nontemporal_load(acc_io + o);
    unsigned i = pA[v], end = pB[v];
    for (; i + 8 <= end; i += 8) {
        int u0 = __builtin_nontemporal_load(col + i);
        int u1 = __builtin_nontemporal_load(col + i + 1);
        int u2 = __builtin_nontemporal_load(col + i + 2);
        int u3 = __builtin_nontemporal_load(col + i + 3);
        int u4 = __builtin_nontemporal_load(col + i + 4);
        int u5 = __builtin_nontemporal_load(col + i + 5);
        int u6 = __builtin_nontemporal_load(col + i + 6);
        int u7 = __builtin_nontemporal_load(col + i + 7);
        float a0 = gin[(size_t)u0 * F_HID + j];
        float a1 = gin[(size_t)u1 * F_HID + j];
        float a2 = gin[(size_t)u2 * F_HID + j];
        float a3 = gin[(size_t)u3 * F_HID + j];
        float a4 = gin[(size_t)u4 * F_HID + j];
        float a5 = gin[(size_t)u5 * F_HID + j];
        float a6 = gin[(size_t)u6 * F_HID + j];
        float a7 = gin[(size_t)u7 * F_HID + j];
        acc += ((a0 + a1) + (a2 + a3)) + ((a4 + a5) + (a6 + a7));
    }
    for (; i < end; ++i)
        acc += gin[(size_t)__builtin_nontemporal_load(col + i) * F_HID + j];
    if (LAST) {
        float di = dinv[v];
        float r;
        if (RELU) r = fmaxf(di * acc + b1[j], 0.f) * di;
        else      r = di * acc;
        __builtin_nontemporal_store(r, acc_io + o);
    } else {
        __builtin_nontemporal_store(acc, acc_io + o);
    }
}

// Node-tiled output GEMM: block owns OUT_NV contiguous nodes; B rows staged
// once in LDS (broadcast reads), outputs written coalesced NT.
// out[v][c] = B[v] . W2[:,c] + b2[c]   (dinv already folded into B)
__global__ void __launch_bounds__(256)
k_out(const float* __restrict__ B,
      const float* __restrict__ W2, const float* __restrict__ b2,
      float* __restrict__ out, int n) {
    __shared__ float w2s[F_HID * F_OUT];   // 8.8 KB
    __shared__ float b2s[F_OUT];
    __shared__ float Bs[OUT_NV][F_HID];    // 1 KB
    int tid = threadIdx.x;
    for (int i = tid; i < F_HID * F_OUT; i += 256) w2s[i] = W2[i];
    if (tid < F_OUT) b2s[tid] = b2[tid];
    int vbase = blockIdx.x * OUT_NV;
    {
        int vl = tid >> 4, j = tid & 15;
        int v = vbase + vl;
        Bs[vl][j] = (v < n) ? B[(size_t)v * F_HID + j] : 0.f;
    }
    __syncthreads();
    const int total = OUT_NV * F_OUT;   // 2208
    for (int q = tid; q < total; q += 256) {
        int vl = q / F_OUT, c = q - vl * F_OUT;
        int v = vbase + vl;
        if (v >= n) continue;
        float acc = b2s[c];
#pragma unroll
        for (int j = 0; j < F_HID; ++j) acc += Bs[vl][j] * w2s[j * F_OUT + c];
        __builtin_nontemporal_store(acc, out + (size_t)v * F_OUT + c);
    }
}

extern "C" void kernel_launch(void* const* d_in, const int* in_sizes, int n_in,
                              void* d_out, int out_size, void* d_ws, size_t ws_size,
                              hipStream_t stream) {
    const float* x   = (const float*)d_in[0];
    const int*   idx = (const int*)d_in[1];
    const float* W1  = (const float*)d_in[2];
    const float* b1  = (const float*)d_in[3];
    const float* W2  = (const float*)d_in[4];
    const float* b2  = (const float*)d_in[5];
    float* out = (float*)d_out;

    const int n = in_sizes[0] / F_IN;       // 100000
    const int E = in_sizes[1] / 2;          // 6400000
    const int s1 = (n + 1) / 2;             // src-slice boundary (3.2 MB halves)

    char* ws = (char*)d_ws;
    size_t off = 0;
    auto carve = [&](size_t bytes) { char* p = ws + off; off += (bytes + 255) / 256 * 256; return p; };
    float*    dinv      = (float*)carve((size_t)n * 4);
    unsigned* bucketPtr = (unsigned*)carve((NBUCK + 1) * 4);
    unsigned* bucketTot = (unsigned*)carve(NBUCK * 4);
    unsigned* cnt       = (unsigned*)carve((size_t)NBUCK * NB * 4);   // 1 MB
    unsigned* p0        = (unsigned*)carve(((size_t)n + 1) * 4);
    unsigned* p1        = (unsigned*)carve((size_t)n * 4);
    float*    bufA      = (float*)carve((size_t)n * F_HID * 4);       // 6.4 MB
    float*    bufB      = (float*)carve((size_t)n * F_HID * 4);       // 6.4 MB
    // binned (E words = 25.6 MB) and col (E words) live in d_out (55.2 MB);
    // both fully consumed before k_out overwrites d_out.
    unsigned* binned = (unsigned*)d_out;
    int*      col    = (int*)d_out + (size_t)E;

    const int B = 256;
    const int nbAgg = (n * F_HID + B - 1) / B;   // 6250
    k_bincount<<<NB, 1024, 0, stream>>>(idx, cnt, E);
    k_scanA   <<<NBUCK, B, 0, stream>>>(cnt, bucketTot);
    k_scanB   <<<1, NBUCK, 0, stream>>>(bucketTot, bucketPtr);
    k_binfill <<<NB, 1024, 0, stream>>>(idx, cnt, bucketPtr, binned, E);
    k_ptrfill <<<NBUCK, 1024, 0, stream>>>(bucketPtr, binned, p0, p1, dinv, col, n, E, s1);
    k_gemm1   <<<(n + 15) / 16, B, 0, stream>>>(x, W1, dinv, bufA, n);
    // layer 1: slice-0 pass (partial), slice-1 pass (+relu epilogue)
    k_agg<1,0,0><<<nbAgg, B, 0, stream>>>(p0, p1,     col, bufA, bufB, dinv, b1, n);
    k_agg<0,1,1><<<nbAgg, B, 0, stream>>>(p1, p0 + 1, col, bufA, bufB, dinv, b1, n);
    // layer 2
    k_agg<1,0,0><<<nbAgg, B, 0, stream>>>(p0, p1,     col, bufB, bufA, dinv, b1, n);
    k_agg<0,1,0><<<nbAgg, B, 0, stream>>>(p1, p0 + 1, col, bufB, bufA, dinv, b1, n);
    k_out     <<<(n + OUT_NV - 1) / OUT_NV, B, 0, stream>>>(bufA, W2, b2, out, n);
}

// Round 14
// 282.526 us; speedup vs baseline: 1.3447x; 1.0634x over previous
//
#include <hip/hip_runtime.h>
#include <cstdint>

#define F_IN  128
#define F_HID 16
#define F_OUT 138
#define NBUCK 512        // dst buckets
#define NPB_SHIFT 8
#define NPB 256          // nodes per bucket
#define NB  512          // edge slabs for binning passes
#define SLAB_CAP 12544   // >= ceil(E/NB) = 12500
#define STAGE_CAP 18432  // >= max bucket edges (~16.4k avg + slack)
#define OUT_NV 16        // nodes per k_out block

typedef float f32x4 __attribute__((ext_vector_type(4)));   // NT-builtin-compatible

// ---------------------------------------------------------------------------
// Inline edge_index dtype detection: int64 (LE, values < 2^31) -> every odd
// int32 word is zero. Returns 2 (int64 stride in words) or 1 (int32).
__device__ __forceinline__ int edge_mult(const int* __restrict__ idx) {
    int nz = 0;
#pragma unroll
    for (int i = 1; i < 64; i += 2) nz |= idx[i];
    return nz ? 1 : 2;
}

// Pass A: per-slab LDS histogram of dst-buckets (reads dst only).
__global__ void __launch_bounds__(1024, 8)
k_bincount(const int* __restrict__ idx, unsigned* __restrict__ cnt, int E) {
    __shared__ unsigned hist[NBUCK];
    int tid = threadIdx.x;
    if (tid < NBUCK) hist[tid] = 0;
    __syncthreads();
    const int mult = edge_mult(idx);
    int slab = (E + NB - 1) / NB;
    int start = blockIdx.x * slab, end = min(E, start + slab);
    if (mult == 2) {
        for (int e = start + tid; e < end; e += 1024)
            atomicAdd(&hist[((const int2*)idx)[(size_t)E + e].x >> NPB_SHIFT], 1u);
    } else {
        for (int e = start + tid; e < end; e += 1024)
            atomicAdd(&hist[idx[(size_t)E + e] >> NPB_SHIFT], 1u);
    }
    __syncthreads();
    if (tid < NBUCK) cnt[(size_t)tid * NB + blockIdx.x] = hist[tid];
}

// Scan step 1: one block per bucket; exclusive-scan its NB slab counts in
// place (pair-per-thread Hillis-Steele); emit bucket total.
__global__ void k_scanA(unsigned* __restrict__ cnt, unsigned* __restrict__ bucketTot) {
    __shared__ unsigned sh[256];
    int t = threadIdx.x;
    unsigned* row = cnt + (size_t)blockIdx.x * NB;
    unsigned e0 = row[2 * t], e1 = row[2 * t + 1];
    unsigned pair = e0 + e1;
    sh[t] = pair;
    __syncthreads();
    for (int off = 1; off < 256; off <<= 1) {
        unsigned v = (t >= off) ? sh[t - off] : 0u;
        __syncthreads();
        sh[t] += v;
        __syncthreads();
    }
    unsigned excl = sh[t] - pair;
    row[2 * t] = excl;
    row[2 * t + 1] = excl + e0;
    if (t == 255) bucketTot[blockIdx.x] = sh[255];
}

// Scan step 2: one block (512 threads); exclusive scan of bucket totals.
__global__ void k_scanB(const unsigned* __restrict__ bucketTot,
                        unsigned* __restrict__ bucketPtr) {
    __shared__ unsigned sh[NBUCK];
    int t = threadIdx.x;
    unsigned c = bucketTot[t];
    sh[t] = c;
    __syncthreads();
    for (int off = 1; off < NBUCK; off <<= 1) {
        unsigned v = (t >= off) ? sh[t - off] : 0u;
        __syncthreads();
        sh[t] += v;
        __syncthreads();
    }
    bucketPtr[t] = sh[t] - c;          // exclusive
    if (t == NBUCK - 1) bucketPtr[NBUCK] = sh[t];
}

// Pass B with LDS write-combining, 1024 threads: histogram slab by bucket,
// scan, scatter the slab's edges into LDS staging sorted by bucket, then
// 16-lane-group copy-out to each (slab,bucket) global segment (~24 entries).
// Packed entry: (dstLocal<<17) | src  (8+17 = 25 bits, src < 2^17).
__global__ void __launch_bounds__(1024, 8)
k_binfill(const int* __restrict__ idx,
          const unsigned* __restrict__ cnt,
          const unsigned* __restrict__ bucketPtr,
          unsigned* __restrict__ binned, int E) {
    __shared__ unsigned hist[NBUCK];
    __shared__ unsigned sofs[NBUCK];
    __shared__ unsigned scur[NBUCK];
    __shared__ unsigned stage[SLAB_CAP];   // 50 KB
    int tid = threadIdx.x;
    if (tid < NBUCK) hist[tid] = 0;
    __syncthreads();
    const int mult = edge_mult(idx);
    int slab = (E + NB - 1) / NB;
    int start = blockIdx.x * slab, end = min(E, start + slab);
    // phase 1: histogram (dst only)
    if (mult == 2) {
        for (int e = start + tid; e < end; e += 1024)
            atomicAdd(&hist[((const int2*)idx)[(size_t)E + e].x >> NPB_SHIFT], 1u);
    } else {
        for (int e = start + tid; e < end; e += 1024)
            atomicAdd(&hist[idx[(size_t)E + e] >> NPB_SHIFT], 1u);
    }
    __syncthreads();
    // phase 2: exclusive scan of NBUCK counts (Hillis-Steele on tid<NBUCK)
    if (tid < NBUCK) scur[tid] = hist[tid];
    __syncthreads();
    for (int off = 1; off < NBUCK; off <<= 1) {
        unsigned v = 0;
        if (tid < NBUCK && tid >= off) v = scur[tid - off];
        __syncthreads();
        if (tid < NBUCK) scur[tid] += v;
        __syncthreads();
    }
    if (tid < NBUCK) {
        unsigned ex = scur[tid] - hist[tid];
        sofs[tid] = ex;
        scur[tid] = ex;
    }
    __syncthreads();
    // phase 3: scatter slab edges into LDS staging sorted by bucket
    for (int e = start + tid; e < end; e += 1024) {
        int s, d;
        if (mult == 2) { s = ((const int2*)idx)[e].x; d = ((const int2*)idx)[(size_t)E + e].x; }
        else           { s = idx[e];                  d = idx[(size_t)E + e]; }
        unsigned pos = atomicAdd(&scur[d >> NPB_SHIFT], 1u);
        stage[pos] = ((unsigned)(d & (NPB - 1)) << 17) | (unsigned)s;
    }
    __syncthreads();
    // phase 4: copy-out, one 16-lane group per bucket segment
    int g = tid >> 4, lane = tid & 15;       // 64 groups
    for (int b = g; b < NBUCK; b += 64) {
        unsigned s0 = sofs[b], len = scur[b] - s0;
        if (len == 0) continue;
        unsigned gbase = cnt[(size_t)b * NB + blockIdx.x] + bucketPtr[b];
        for (unsigned i = lane; i < len; i += 16)
            binned[gbase + i] = stage[s0 + i];
    }
}

// Fused per-bucket (1024 threads): slice-aware degree histogram -> scan ->
// p0/p1 + dinv, then sort the bucket's edges into LDS staging by (node,
// slice) and stream out col[] as one coalesced sequential copy.
__global__ void __launch_bounds__(1024, 8)
k_ptrfill(const unsigned* __restrict__ bucketPtr,
          const unsigned* __restrict__ binned,
          unsigned* __restrict__ p0, unsigned* __restrict__ p1,
          float* __restrict__ dinv, int* __restrict__ col,
          int n, int E, int s1) {
    __shared__ unsigned deg0[NPB], deg1[NPB];
    __shared__ unsigned cur0[NPB], cur1[NPB];
    __shared__ unsigned sh[NPB];
    __shared__ unsigned stage[STAGE_CAP];   // 72 KB
    int tid = threadIdx.x, bb = blockIdx.x;
    if (tid < NPB) { deg0[tid] = 0; deg1[tid] = 0; }
    __syncthreads();
    unsigned start = bucketPtr[bb], end = bucketPtr[bb + 1];
    unsigned cntE = end - start;
    for (unsigned i = start + tid; i < end; i += 1024) {
        unsigned entry = binned[i];
        int dl = (int)(entry >> 17);
        int src = (int)(entry & 0x1FFFFu);
        atomicAdd(src >= s1 ? &deg1[dl] : &deg0[dl], 1u);
    }
    __syncthreads();
    unsigned d0 = 0, d1 = 0, tot = 0;
    if (tid < NPB) { d0 = deg0[tid]; d1 = deg1[tid]; tot = d0 + d1; sh[tid] = tot; }
    __syncthreads();
    for (int off = 1; off < NPB; off <<= 1) {
        unsigned v = 0;
        if (tid < NPB && tid >= off) v = sh[tid - off];
        __syncthreads();
        if (tid < NPB) sh[tid] += v;
        __syncthreads();
    }
    if (tid < NPB) {
        unsigned lbase = sh[tid] - tot;       // exclusive prefix (local)
        cur0[tid] = lbase;
        cur1[tid] = lbase + d0;
        int v = (bb << NPB_SHIFT) + tid;
        if (v < n) {
            p0[v] = start + lbase;
            p1[v] = start + lbase + d0;
            dinv[v] = rsqrtf((float)(tot + 1u));   // +1 self-loop
        }
    }
    if (bb == 0 && tid == 0) p0[n] = (unsigned)E;
    __syncthreads();
    if (cntE <= STAGE_CAP) {
        for (unsigned i = start + tid; i < end; i += 1024) {
            unsigned entry = binned[i];
            int dl = (int)(entry >> 17);
            unsigned src = entry & 0x1FFFFu;
            unsigned pos = atomicAdd((int)src >= s1 ? &cur1[dl] : &cur0[dl], 1u);
            stage[pos] = src;
        }
        __syncthreads();
        for (unsigned i = tid; i < cntE; i += 1024)
            col[start + i] = (int)stage[i];
    } else {
        for (unsigned i = start + tid; i < end; i += 1024) {
            unsigned entry = binned[i];
            int dl = (int)(entry >> 17);
            unsigned src = entry & 0x1FFFFu;
            unsigned pos = atomicAdd((int)src >= s1 ? &cur1[dl] : &cur0[dl], 1u);
            col[start + pos] = (int)src;
        }
    }
}

// g1[v][j] = dinv[v] * (x[v] . W1[:,j]).  16 nodes x 16 feats per block.
__global__ void k_gemm1(const float* __restrict__ x, const float* __restrict__ W1,
                        const float* __restrict__ dinv,
                        float* __restrict__ g1, int n) {
    __shared__ float w1s[F_IN * F_HID];     // 8 KB
    __shared__ float xs[16][F_IN + 4];
    int tid = threadIdx.x;
    for (int i = tid; i < F_IN * F_HID; i += 256) w1s[i] = W1[i];
    int nb = blockIdx.x * 16;
    for (int q = tid; q < 512; q += 256) {
        int r = q >> 5, k4 = q & 31;
        int g = nb + r;
        float4 v = make_float4(0.f, 0.f, 0.f, 0.f);
        if (g < n) v = ((const float4*)x)[(size_t)g * 32 + k4];
        xs[r][k4 * 4 + 0] = v.x; xs[r][k4 * 4 + 1] = v.y;
        xs[r][k4 * 4 + 2] = v.z; xs[r][k4 * 4 + 3] = v.w;
    }
    __syncthreads();
    int r = tid >> 4, j = tid & 15;
    int g = nb + r;
    if (g < n) {
        float acc = 0.f;
#pragma unroll
        for (int k = 0; k < F_IN; ++k) acc += xs[r][k] * w1s[k * F_HID + j];
        g1[(size_t)g * F_HID + j] = acc * dinv[g];
    }
}

// Pull-mode CSR aggregation over ONE src slice. 4 lanes per node, each
// gathering 16 B (f32x4) of the 64 B row -> one gather INSTRUCTION covers
// 16 edges per wave (vs 4 with scalar lanes): 4x fewer memory instructions,
// same byte traffic, same 64 B/edge coalescing. gin slice is XCD-L2
// resident; col streamed NT; partial accumulator streamed NT.
template <int FIRST, int LAST, int RELU>
__global__ void __launch_bounds__(256)
k_agg(const unsigned* __restrict__ pA, const unsigned* __restrict__ pB,
      const int* __restrict__ col,
      const f32x4* __restrict__ gin4, f32x4* __restrict__ acc_io,
      const float* __restrict__ dinv, const f32x4* __restrict__ b1q, int n) {
    int t = blockIdx.x * blockDim.x + threadIdx.x;
    int v = t >> 2, q = t & 3;            // q = f32x4 column of the row
    if (v >= n) return;
    size_t o = (size_t)v * 4 + q;
    f32x4 acc;
    if (FIRST) acc = gin4[o];                              // self-loop
    else       acc = __builtin_nontemporal_load(acc_io + o);
    unsigned i = pA[v], end = pB[v];
    for (; i + 8 <= end; i += 8) {
        int u0 = __builtin_nontemporal_load(col + i);
        int u1 = __builtin_nontemporal_load(col + i + 1);
        int u2 = __builtin_nontemporal_load(col + i + 2);
        int u3 = __builtin_nontemporal_load(col + i + 3);
        int u4 = __builtin_nontemporal_load(col + i + 4);
        int u5 = __builtin_nontemporal_load(col + i + 5);
        int u6 = __builtin_nontemporal_load(col + i + 6);
        int u7 = __builtin_nontemporal_load(col + i + 7);
        f32x4 a0 = gin4[(size_t)u0 * 4 + q];
        f32x4 a1 = gin4[(size_t)u1 * 4 + q];
        f32x4 a2 = gin4[(size_t)u2 * 4 + q];
        f32x4 a3 = gin4[(size_t)u3 * 4 + q];
        f32x4 a4 = gin4[(size_t)u4 * 4 + q];
        f32x4 a5 = gin4[(size_t)u5 * 4 + q];
        f32x4 a6 = gin4[(size_t)u6 * 4 + q];
        f32x4 a7 = gin4[(size_t)u7 * 4 + q];
        acc += ((a0 + a1) + (a2 + a3)) + ((a4 + a5) + (a6 + a7));
    }
    for (; i < end; ++i)
        acc += gin4[(size_t)__builtin_nontemporal_load(col + i) * 4 + q];
    if (LAST) {
        float di = dinv[v];
        f32x4 r;
        if (RELU) {
            f32x4 b = b1q[q];
            r.x = fmaxf(di * acc.x + b.x, 0.f) * di;
            r.y = fmaxf(di * acc.y + b.y, 0.f) * di;
            r.z = fmaxf(di * acc.z + b.z, 0.f) * di;
            r.w = fmaxf(di * acc.w + b.w, 0.f) * di;
        } else {
            r = acc * di;
        }
        __builtin_nontemporal_store(r, acc_io + o);
    } else {
        __builtin_nontemporal_store(acc, acc_io + o);
    }
}

// Node-tiled output GEMM: block owns OUT_NV contiguous nodes; B rows staged
// once in LDS (broadcast reads), outputs written coalesced NT.
// out[v][c] = B[v] . W2[:,c] + b2[c]   (dinv already folded into B)
__global__ void __launch_bounds__(256)
k_out(const float* __restrict__ B,
      const float* __restrict__ W2, const float* __restrict__ b2,
      float* __restrict__ out, int n) {
    __shared__ float w2s[F_HID * F_OUT];   // 8.8 KB
    __shared__ float b2s[F_OUT];
    __shared__ float Bs[OUT_NV][F_HID];    // 1 KB
    int tid = threadIdx.x;
    for (int i = tid; i < F_HID * F_OUT; i += 256) w2s[i] = W2[i];
    if (tid < F_OUT) b2s[tid] = b2[tid];
    int vbase = blockIdx.x * OUT_NV;
    {
        int vl = tid >> 4, j = tid & 15;
        int v = vbase + vl;
        Bs[vl][j] = (v < n) ? B[(size_t)v * F_HID + j] : 0.f;
    }
    __syncthreads();
    const int total = OUT_NV * F_OUT;   // 2208
    for (int q = tid; q < total; q += 256) {
        int vl = q / F_OUT, c = q - vl * F_OUT;
        int v = vbase + vl;
        if (v >= n) continue;
        float acc = b2s[c];
#pragma unroll
        for (int j = 0; j < F_HID; ++j) acc += Bs[vl][j] * w2s[j * F_OUT + c];
        __builtin_nontemporal_store(acc, out + (size_t)v * F_OUT + c);
    }
}

extern "C" void kernel_launch(void* const* d_in, const int* in_sizes, int n_in,
                              void* d_out, int out_size, void* d_ws, size_t ws_size,
                              hipStream_t stream) {
    const float* x   = (const float*)d_in[0];
    const int*   idx = (const int*)d_in[1];
    const float* W1  = (const float*)d_in[2];
    const float* b1  = (const float*)d_in[3];
    const float* W2  = (const float*)d_in[4];
    const float* b2  = (const float*)d_in[5];
    float* out = (float*)d_out;

    const int n = in_sizes[0] / F_IN;       // 100000
    const int E = in_sizes[1] / 2;          // 6400000
    const int s1 = (n + 1) / 2;             // src-slice boundary (3.2 MB halves)

    char* ws = (char*)d_ws;
    size_t off = 0;
    auto carve = [&](size_t bytes) { char* p = ws + off; off += (bytes + 255) / 256 * 256; return p; };
    float*    dinv      = (float*)carve((size_t)n * 4);
    unsigned* bucketPtr = (unsigned*)carve((NBUCK + 1) * 4);
    unsigned* bucketTot = (unsigned*)carve(NBUCK * 4);
    unsigned* cnt       = (unsigned*)carve((size_t)NBUCK * NB * 4);   // 1 MB
    unsigned* p0        = (unsigned*)carve(((size_t)n + 1) * 4);
    unsigned* p1        = (unsigned*)carve((size_t)n * 4);
    float*    bufA      = (float*)carve((size_t)n * F_HID * 4);       // 6.4 MB
    float*    bufB      = (float*)carve((size_t)n * F_HID * 4);       // 6.4 MB
    // binned (E words = 25.6 MB) and col (E words) live in d_out (55.2 MB);
    // both fully consumed before k_out overwrites d_out.
    unsigned* binned = (unsigned*)d_out;
    int*      col    = (int*)d_out + (size_t)E;

    const int B = 256;
    const int nbAgg4 = (n * 4 + B - 1) / B;   // 1563
    k_bincount<<<NB, 1024, 0, stream>>>(idx, cnt, E);
    k_scanA   <<<NBUCK, B, 0, stream>>>(cnt, bucketTot);
    k_scanB   <<<1, NBUCK, 0, stream>>>(bucketTot, bucketPtr);
    k_binfill <<<NB, 1024, 0, stream>>>(idx, cnt, bucketPtr, binned, E);
    k_ptrfill <<<NBUCK, 1024, 0, stream>>>(bucketPtr, binned, p0, p1, dinv, col, n, E, s1);
    k_gemm1   <<<(n + 15) / 16, B, 0, stream>>>(x, W1, dinv, bufA, n);
    // layer 1: slice-0 pass (partial), slice-1 pass (+relu epilogue)
    k_agg<1,0,0><<<nbAgg4, B, 0, stream>>>(p0, p1,     col, (const f32x4*)bufA,
                                           (f32x4*)bufB, dinv, (const f32x4*)b1, n);
    k_agg<0,1,1><<<nbAgg4, B, 0, stream>>>(p1, p0 + 1, col, (const f32x4*)bufA,
                                           (f32x4*)bufB, dinv, (const f32x4*)b1, n);
    // layer 2
    k_agg<1,0,0><<<nbAgg4, B, 0, stream>>>(p0, p1,     col, (const f32x4*)bufB,
                                           (f32x4*)bufA, dinv, (const f32x4*)b1, n);
    k_agg<0,1,0><<<nbAgg4, B, 0, stream>>>(p1, p0 + 1, col, (const f32x4*)bufB,
                                           (f32x4*)bufA, dinv, (const f32x4*)b1, n);
    k_out     <<<(n + OUT_NV - 1) / OUT_NV, B, 0, stream>>>(bufA, W2, b2, out, n);
}

// Round 15
// 277.403 us; speedup vs baseline: 1.3696x; 1.0185x over previous
//
#include <hip/hip_runtime.h>
#include <cstdint>

#define F_IN  128
#define F_HID 16
#define F_OUT 138
#define NBUCK 512        // dst buckets
#define NPB_SHIFT 8
#define NPB 256          // nodes per bucket
#define NB  512          // edge slabs for binning passes
#define SLAB_CAP 12544   // >= ceil(E/NB) = 12500
#define STAGE_CAP 18432  // >= max bucket edges (~16.4k avg + slack)
#define OUT_NV 16        // nodes per k_out block

typedef float f32x4 __attribute__((ext_vector_type(4)));   // NT-builtin-compatible

// ---------------------------------------------------------------------------
// Inline edge_index dtype detection: int64 (LE, values < 2^31) -> every odd
// int32 word is zero. Returns 2 (int64 stride in words) or 1 (int32).
__device__ __forceinline__ int edge_mult(const int* __restrict__ idx) {
    int nz = 0;
#pragma unroll
    for (int i = 1; i < 64; i += 2) nz |= idx[i];
    return nz ? 1 : 2;
}

// Pass A: per-slab LDS histogram of dst-buckets (reads dst only).
__global__ void __launch_bounds__(1024, 8)
k_bincount(const int* __restrict__ idx, unsigned* __restrict__ cnt, int E) {
    __shared__ unsigned hist[NBUCK];
    int tid = threadIdx.x;
    if (tid < NBUCK) hist[tid] = 0;
    __syncthreads();
    const int mult = edge_mult(idx);
    int slab = (E + NB - 1) / NB;
    int start = blockIdx.x * slab, end = min(E, start + slab);
    if (mult == 2) {
        for (int e = start + tid; e < end; e += 1024)
            atomicAdd(&hist[((const int2*)idx)[(size_t)E + e].x >> NPB_SHIFT], 1u);
    } else {
        for (int e = start + tid; e < end; e += 1024)
            atomicAdd(&hist[idx[(size_t)E + e] >> NPB_SHIFT], 1u);
    }
    __syncthreads();
    if (tid < NBUCK) cnt[(size_t)tid * NB + blockIdx.x] = hist[tid];
}

// Scan step 1: one block per bucket; exclusive-scan its NB slab counts in
// place (pair-per-thread Hillis-Steele); emit bucket total.
__global__ void k_scanA(unsigned* __restrict__ cnt, unsigned* __restrict__ bucketTot) {
    __shared__ unsigned sh[256];
    int t = threadIdx.x;
    unsigned* row = cnt + (size_t)blockIdx.x * NB;
    unsigned e0 = row[2 * t], e1 = row[2 * t + 1];
    unsigned pair = e0 + e1;
    sh[t] = pair;
    __syncthreads();
    for (int off = 1; off < 256; off <<= 1) {
        unsigned v = (t >= off) ? sh[t - off] : 0u;
        __syncthreads();
        sh[t] += v;
        __syncthreads();
    }
    unsigned excl = sh[t] - pair;
    row[2 * t] = excl;
    row[2 * t + 1] = excl + e0;
    if (t == 255) bucketTot[blockIdx.x] = sh[255];
}

// Scan step 2: one block (512 threads); exclusive scan of bucket totals.
__global__ void k_scanB(const unsigned* __restrict__ bucketTot,
                        unsigned* __restrict__ bucketPtr) {
    __shared__ unsigned sh[NBUCK];
    int t = threadIdx.x;
    unsigned c = bucketTot[t];
    sh[t] = c;
    __syncthreads();
    for (int off = 1; off < NBUCK; off <<= 1) {
        unsigned v = (t >= off) ? sh[t - off] : 0u;
        __syncthreads();
        sh[t] += v;
        __syncthreads();
    }
    bucketPtr[t] = sh[t] - c;          // exclusive
    if (t == NBUCK - 1) bucketPtr[NBUCK] = sh[t];
}

// Pass B with LDS write-combining, 1024 threads: histogram slab by bucket,
// scan, scatter the slab's edges into LDS staging sorted by bucket, then
// 16-lane-group copy-out to each (slab,bucket) global segment (~24 entries).
// Packed entry: (dstLocal<<17) | src  (8+17 = 25 bits, src < 2^17).
__global__ void __launch_bounds__(1024, 8)
k_binfill(const int* __restrict__ idx,
          const unsigned* __restrict__ cnt,
          const unsigned* __restrict__ bucketPtr,
          unsigned* __restrict__ binned, int E) {
    __shared__ unsigned hist[NBUCK];
    __shared__ unsigned sofs[NBUCK];
    __shared__ unsigned scur[NBUCK];
    __shared__ unsigned stage[SLAB_CAP];   // 50 KB
    int tid = threadIdx.x;
    if (tid < NBUCK) hist[tid] = 0;
    __syncthreads();
    const int mult = edge_mult(idx);
    int slab = (E + NB - 1) / NB;
    int start = blockIdx.x * slab, end = min(E, start + slab);
    // phase 1: histogram (dst only)
    if (mult == 2) {
        for (int e = start + tid; e < end; e += 1024)
            atomicAdd(&hist[((const int2*)idx)[(size_t)E + e].x >> NPB_SHIFT], 1u);
    } else {
        for (int e = start + tid; e < end; e += 1024)
            atomicAdd(&hist[idx[(size_t)E + e] >> NPB_SHIFT], 1u);
    }
    __syncthreads();
    // phase 2: exclusive scan of NBUCK counts (Hillis-Steele on tid<NBUCK)
    if (tid < NBUCK) scur[tid] = hist[tid];
    __syncthreads();
    for (int off = 1; off < NBUCK; off <<= 1) {
        unsigned v = 0;
        if (tid < NBUCK && tid >= off) v = scur[tid - off];
        __syncthreads();
        if (tid < NBUCK) scur[tid] += v;
        __syncthreads();
    }
    if (tid < NBUCK) {
        unsigned ex = scur[tid] - hist[tid];
        sofs[tid] = ex;
        scur[tid] = ex;
    }
    __syncthreads();
    // phase 3: scatter slab edges into LDS staging sorted by bucket
    for (int e = start + tid; e < end; e += 1024) {
        int s, d;
        if (mult == 2) { s = ((const int2*)idx)[e].x; d = ((const int2*)idx)[(size_t)E + e].x; }
        else           { s = idx[e];                  d = idx[(size_t)E + e]; }
        unsigned pos = atomicAdd(&scur[d >> NPB_SHIFT], 1u);
        stage[pos] = ((unsigned)(d & (NPB - 1)) << 17) | (unsigned)s;
    }
    __syncthreads();
    // phase 4: copy-out, one 16-lane group per bucket segment
    int g = tid >> 4, lane = tid & 15;       // 64 groups
    for (int b = g; b < NBUCK; b += 64) {
        unsigned s0 = sofs[b], len = scur[b] - s0;
        if (len == 0) continue;
        unsigned gbase = cnt[(size_t)b * NB + blockIdx.x] + bucketPtr[b];
        for (unsigned i = lane; i < len; i += 16)
            binned[gbase + i] = stage[s0 + i];
    }
}

// Fused per-bucket (1024 threads): degree histogram -> scan -> ptr + dinv,
// then sort the bucket's edges into LDS staging by node and stream out
// col[] as one coalesced sequential copy (fallback: direct scatter).
__global__ void __launch_bounds__(1024, 8)
k_ptrfill(const unsigned* __restrict__ bucketPtr,
          const unsigned* __restrict__ binned,
          unsigned* __restrict__ p0,
          float* __restrict__ dinv, int* __restrict__ col,
          int n, int E) {
    __shared__ unsigned deg[NPB];
    __shared__ unsigned cur[NPB];
    __shared__ unsigned sh[NPB];
    __shared__ unsigned stage[STAGE_CAP];   // 72 KB
    int tid = threadIdx.x, bb = blockIdx.x;
    if (tid < NPB) deg[tid] = 0;
    __syncthreads();
    unsigned start = bucketPtr[bb], end = bucketPtr[bb + 1];
    unsigned cntE = end - start;
    for (unsigned i = start + tid; i < end; i += 1024)
        atomicAdd(&deg[binned[i] >> 17], 1u);
    __syncthreads();
    unsigned d0 = 0;
    if (tid < NPB) { d0 = deg[tid]; sh[tid] = d0; }
    __syncthreads();
    for (int off = 1; off < NPB; off <<= 1) {
        unsigned v = 0;
        if (tid < NPB && tid >= off) v = sh[tid - off];
        __syncthreads();
        if (tid < NPB) sh[tid] += v;
        __syncthreads();
    }
    if (tid < NPB) {
        unsigned lbase = sh[tid] - d0;        // exclusive prefix (local)
        cur[tid] = lbase;
        int v = (bb << NPB_SHIFT) + tid;
        if (v < n) {
            p0[v] = start + lbase;
            dinv[v] = rsqrtf((float)(d0 + 1u));   // +1 self-loop
        }
    }
    if (bb == 0 && tid == 0) p0[n] = (unsigned)E;
    __syncthreads();
    if (cntE <= STAGE_CAP) {
        for (unsigned i = start + tid; i < end; i += 1024) {
            unsigned entry = binned[i];
            unsigned pos = atomicAdd(&cur[entry >> 17], 1u);
            stage[pos] = entry & 0x1FFFFu;
        }
        __syncthreads();
        for (unsigned i = tid; i < cntE; i += 1024)
            col[start + i] = (int)stage[i];
    } else {
        for (unsigned i = start + tid; i < end; i += 1024) {
            unsigned entry = binned[i];
            unsigned pos = atomicAdd(&cur[entry >> 17], 1u);
            col[start + pos] = (int)(entry & 0x1FFFFu);
        }
    }
}

// g1[v][j] = dinv[v] * (x[v] . W1[:,j]).  16 nodes x 16 feats per block.
__global__ void k_gemm1(const float* __restrict__ x, const float* __restrict__ W1,
                        const float* __restrict__ dinv,
                        float* __restrict__ g1, int n) {
    __shared__ float w1s[F_IN * F_HID];     // 8 KB
    __shared__ float xs[16][F_IN + 4];
    int tid = threadIdx.x;
    for (int i = tid; i < F_IN * F_HID; i += 256) w1s[i] = W1[i];
    int nb = blockIdx.x * 16;
    for (int q = tid; q < 512; q += 256) {
        int r = q >> 5, k4 = q & 31;
        int g = nb + r;
        float4 v = make_float4(0.f, 0.f, 0.f, 0.f);
        if (g < n) v = ((const float4*)x)[(size_t)g * 32 + k4];
        xs[r][k4 * 4 + 0] = v.x; xs[r][k4 * 4 + 1] = v.y;
        xs[r][k4 * 4 + 2] = v.z; xs[r][k4 * 4 + 3] = v.w;
    }
    __syncthreads();
    int r = tid >> 4, j = tid & 15;
    int g = nb + r;
    if (g < n) {
        float acc = 0.f;
#pragma unroll
        for (int k = 0; k < F_IN; ++k) acc += xs[r][k] * w1s[k * F_HID + j];
        g1[(size_t)g * F_HID + j] = acc * dinv[g];
    }
}

// Pull-mode CSR aggregation, FULL row range per node (no src slicing — the
// latency-bound regime favors longer inner loops and no partial-acc stream).
// 4 lanes per node, each gathering 16 B (f32x4) of the 64 B row. Self-loop =
// accumulator init; epilogue fused (RELU=1: relu(dinv*acc+b1)*dinv, else
// dinv*acc). col streamed NT; output streamed NT.
template <int RELU>
__global__ void __launch_bounds__(256)
k_agg(const unsigned* __restrict__ p0, const int* __restrict__ col,
      const f32x4* __restrict__ gin4, f32x4* __restrict__ gout,
      const float* __restrict__ dinv, const f32x4* __restrict__ b1q, int n) {
    int t = blockIdx.x * blockDim.x + threadIdx.x;
    int v = t >> 2, q = t & 3;            // q = f32x4 column of the row
    if (v >= n) return;
    size_t o = (size_t)v * 4 + q;
    f32x4 acc = gin4[o];                  // self-loop
    unsigned i = p0[v], end = p0[v + 1];
    for (; i + 8 <= end; i += 8) {
        int u0 = __builtin_nontemporal_load(col + i);
        int u1 = __builtin_nontemporal_load(col + i + 1);
        int u2 = __builtin_nontemporal_load(col + i + 2);
        int u3 = __builtin_nontemporal_load(col + i + 3);
        int u4 = __builtin_nontemporal_load(col + i + 4);
        int u5 = __builtin_nontemporal_load(col + i + 5);
        int u6 = __builtin_nontemporal_load(col + i + 6);
        int u7 = __builtin_nontemporal_load(col + i + 7);
        f32x4 a0 = gin4[(size_t)u0 * 4 + q];
        f32x4 a1 = gin4[(size_t)u1 * 4 + q];
        f32x4 a2 = gin4[(size_t)u2 * 4 + q];
        f32x4 a3 = gin4[(size_t)u3 * 4 + q];
        f32x4 a4 = gin4[(size_t)u4 * 4 + q];
        f32x4 a5 = gin4[(size_t)u5 * 4 + q];
        f32x4 a6 = gin4[(size_t)u6 * 4 + q];
        f32x4 a7 = gin4[(size_t)u7 * 4 + q];
        acc += ((a0 + a1) + (a2 + a3)) + ((a4 + a5) + (a6 + a7));
    }
    for (; i < end; ++i)
        acc += gin4[(size_t)__builtin_nontemporal_load(col + i) * 4 + q];
    float di = dinv[v];
    f32x4 r;
    if (RELU) {
        f32x4 b = b1q[q];
        r.x = fmaxf(di * acc.x + b.x, 0.f) * di;
        r.y = fmaxf(di * acc.y + b.y, 0.f) * di;
        r.z = fmaxf(di * acc.z + b.z, 0.f) * di;
        r.w = fmaxf(di * acc.w + b.w, 0.f) * di;
    } else {
        r = acc * di;
    }
    __builtin_nontemporal_store(r, gout + o);
}

// Node-tiled output GEMM: block owns OUT_NV contiguous nodes; B rows staged
// once in LDS (broadcast reads), outputs written coalesced NT.
// out[v][c] = B[v] . W2[:,c] + b2[c]   (dinv already folded into B)
__global__ void __launch_bounds__(256)
k_out(const float* __restrict__ B,
      const float* __restrict__ W2, const float* __restrict__ b2,
      float* __restrict__ out, int n) {
    __shared__ float w2s[F_HID * F_OUT];   // 8.8 KB
    __shared__ float b2s[F_OUT];
    __shared__ float Bs[OUT_NV][F_HID];    // 1 KB
    int tid = threadIdx.x;
    for (int i = tid; i < F_HID * F_OUT; i += 256) w2s[i] = W2[i];
    if (tid < F_OUT) b2s[tid] = b2[tid];
    int vbase = blockIdx.x * OUT_NV;
    {
        int vl = tid >> 4, j = tid & 15;
        int v = vbase + vl;
        Bs[vl][j] = (v < n) ? B[(size_t)v * F_HID + j] : 0.f;
    }
    __syncthreads();
    const int total = OUT_NV * F_OUT;   // 2208
    for (int q = tid; q < total; q += 256) {
        int vl = q / F_OUT, c = q - vl * F_OUT;
        int v = vbase + vl;
        if (v >= n) continue;
        float acc = b2s[c];
#pragma unroll
        for (int j = 0; j < F_HID; ++j) acc += Bs[vl][j] * w2s[j * F_OUT + c];
        __builtin_nontemporal_store(acc, out + (size_t)v * F_OUT + c);
    }
}

extern "C" void kernel_launch(void* const* d_in, const int* in_sizes, int n_in,
                              void* d_out, int out_size, void* d_ws, size_t ws_size,
                              hipStream_t stream) {
    const float* x   = (const float*)d_in[0];
    const int*   idx = (const int*)d_in[1];
    const float* W1  = (const float*)d_in[2];
    const float* b1  = (const float*)d_in[3];
    const float* W2  = (const float*)d_in[4];
    const float* b2  = (const float*)d_in[5];
    float* out = (float*)d_out;

    const int n = in_sizes[0] / F_IN;       // 100000
    const int E = in_sizes[1] / 2;          // 6400000

    char* ws = (char*)d_ws;
    size_t off = 0;
    auto carve = [&](size_t bytes) { char* p = ws + off; off += (bytes + 255) / 256 * 256; return p; };
    float*    dinv      = (float*)carve((size_t)n * 4);
    unsigned* bucketPtr = (unsigned*)carve((NBUCK + 1) * 4);
    unsigned* bucketTot = (unsigned*)carve(NBUCK * 4);
    unsigned* cnt       = (unsigned*)carve((size_t)NBUCK * NB * 4);   // 1 MB
    unsigned* p0        = (unsigned*)carve(((size_t)n + 1) * 4);
    float*    bufA      = (float*)carve((size_t)n * F_HID * 4);       // 6.4 MB
    float*    bufB      = (float*)carve((size_t)n * F_HID * 4);       // 6.4 MB
    // binned (E words = 25.6 MB) and col (E words) live in d_out (55.2 MB);
    // both fully consumed before k_out overwrites d_out.
    unsigned* binned = (unsigned*)d_out;
    int*      col    = (int*)d_out + (size_t)E;

    const int B = 256;
    const int nbAgg4 = (n * 4 + B - 1) / B;   // 1563
    k_bincount<<<NB, 1024, 0, stream>>>(idx, cnt, E);
    k_scanA   <<<NBUCK, B, 0, stream>>>(cnt, bucketTot);
    k_scanB   <<<1, NBUCK, 0, stream>>>(bucketTot, bucketPtr);
    k_binfill <<<NB, 1024, 0, stream>>>(idx, cnt, bucketPtr, binned, E);
    k_ptrfill <<<NBUCK, 1024, 0, stream>>>(bucketPtr, binned, p0, dinv, col, n, E);
    k_gemm1   <<<(n + 15) / 16, B, 0, stream>>>(x, W1, dinv, bufA, n);
    // layer 1 (full-range pass, fused relu epilogue)
    k_agg<1>  <<<nbAgg4, B, 0, stream>>>(p0, col, (const f32x4*)bufA,
                                         (f32x4*)bufB, dinv, (const f32x4*)b1, n);
    // layer 2
    k_agg<0>  <<<nbAgg4, B, 0, stream>>>(p0, col, (const f32x4*)bufB,
                                         (f32x4*)bufA, dinv, (const f32x4*)b1, n);
    k_out     <<<(n + OUT_NV - 1) / OUT_NV, B, 0, stream>>>(bufA, W2, b2, out, n);
}

// Round 16
// 248.366 us; speedup vs baseline: 1.5297x; 1.1169x over previous
//
#include <hip/hip_runtime.h>
#include <cstdint>

#define F_IN  128
#define F_HID 16
#define F_OUT 138
#define NBUCK 512        // dst buckets
#define NPB_SHIFT 8
#define NPB 256          // nodes per bucket
#define NB  512          // edge slabs for binning passes
#define SLAB_CAP 12544   // >= ceil(E/NB) = 12500
#define STAGE_CAP 18432  // >= max bucket edges (~16.4k avg + slack)
#define OUT_NV 16        // nodes per k_out block

typedef float f32x4 __attribute__((ext_vector_type(4)));
typedef float f32x8 __attribute__((ext_vector_type(8)));
typedef _Float16 h16;
typedef _Float16 h16x8 __attribute__((ext_vector_type(8)));   // 16 B

// ---------------------------------------------------------------------------
// Inline edge_index dtype detection: int64 (LE, values < 2^31) -> every odd
// int32 word is zero. Returns 2 (int64 stride in words) or 1 (int32).
__device__ __forceinline__ int edge_mult(const int* __restrict__ idx) {
    int nz = 0;
#pragma unroll
    for (int i = 1; i < 64; i += 2) nz |= idx[i];
    return nz ? 1 : 2;
}

// Pass A: per-slab LDS histogram of dst-buckets (reads dst only).
__global__ void __launch_bounds__(1024, 8)
k_bincount(const int* __restrict__ idx, unsigned* __restrict__ cnt, int E) {
    __shared__ unsigned hist[NBUCK];
    int tid = threadIdx.x;
    if (tid < NBUCK) hist[tid] = 0;
    __syncthreads();
    const int mult = edge_mult(idx);
    int slab = (E + NB - 1) / NB;
    int start = blockIdx.x * slab, end = min(E, start + slab);
    if (mult == 2) {
        for (int e = start + tid; e < end; e += 1024)
            atomicAdd(&hist[((const int2*)idx)[(size_t)E + e].x >> NPB_SHIFT], 1u);
    } else {
        for (int e = start + tid; e < end; e += 1024)
            atomicAdd(&hist[idx[(size_t)E + e] >> NPB_SHIFT], 1u);
    }
    __syncthreads();
    if (tid < NBUCK) cnt[(size_t)tid * NB + blockIdx.x] = hist[tid];
}

// Scan step 1: one block per bucket; exclusive-scan its NB slab counts in
// place (pair-per-thread Hillis-Steele); emit bucket total.
__global__ void k_scanA(unsigned* __restrict__ cnt, unsigned* __restrict__ bucketTot) {
    __shared__ unsigned sh[256];
    int t = threadIdx.x;
    unsigned* row = cnt + (size_t)blockIdx.x * NB;
    unsigned e0 = row[2 * t], e1 = row[2 * t + 1];
    unsigned pair = e0 + e1;
    sh[t] = pair;
    __syncthreads();
    for (int off = 1; off < 256; off <<= 1) {
        unsigned v = (t >= off) ? sh[t - off] : 0u;
        __syncthreads();
        sh[t] += v;
        __syncthreads();
    }
    unsigned excl = sh[t] - pair;
    row[2 * t] = excl;
    row[2 * t + 1] = excl + e0;
    if (t == 255) bucketTot[blockIdx.x] = sh[255];
}

// Scan step 2: one block (512 threads); exclusive scan of bucket totals.
__global__ void k_scanB(const unsigned* __restrict__ bucketTot,
                        unsigned* __restrict__ bucketPtr) {
    __shared__ unsigned sh[NBUCK];
    int t = threadIdx.x;
    unsigned c = bucketTot[t];
    sh[t] = c;
    __syncthreads();
    for (int off = 1; off < NBUCK; off <<= 1) {
        unsigned v = (t >= off) ? sh[t - off] : 0u;
        __syncthreads();
        sh[t] += v;
        __syncthreads();
    }
    bucketPtr[t] = sh[t] - c;          // exclusive
    if (t == NBUCK - 1) bucketPtr[NBUCK] = sh[t];
}

// Pass B with LDS write-combining, 1024 threads: histogram slab by bucket,
// scan, scatter the slab's edges into LDS staging sorted by bucket, then
// 16-lane-group copy-out to each (slab,bucket) global segment (~24 entries).
// Packed entry: (dstLocal<<17) | src  (8+17 = 25 bits, src < 2^17).
__global__ void __launch_bounds__(1024, 8)
k_binfill(const int* __restrict__ idx,
          const unsigned* __restrict__ cnt,
          const unsigned* __restrict__ bucketPtr,
          unsigned* __restrict__ binned, int E) {
    __shared__ unsigned hist[NBUCK];
    __shared__ unsigned sofs[NBUCK];
    __shared__ unsigned scur[NBUCK];
    __shared__ unsigned stage[SLAB_CAP];   // 50 KB
    int tid = threadIdx.x;
    if (tid < NBUCK) hist[tid] = 0;
    __syncthreads();
    const int mult = edge_mult(idx);
    int slab = (E + NB - 1) / NB;
    int start = blockIdx.x * slab, end = min(E, start + slab);
    // phase 1: histogram (dst only)
    if (mult == 2) {
        for (int e = start + tid; e < end; e += 1024)
            atomicAdd(&hist[((const int2*)idx)[(size_t)E + e].x >> NPB_SHIFT], 1u);
    } else {
        for (int e = start + tid; e < end; e += 1024)
            atomicAdd(&hist[idx[(size_t)E + e] >> NPB_SHIFT], 1u);
    }
    __syncthreads();
    // phase 2: exclusive scan of NBUCK counts (Hillis-Steele on tid<NBUCK)
    if (tid < NBUCK) scur[tid] = hist[tid];
    __syncthreads();
    for (int off = 1; off < NBUCK; off <<= 1) {
        unsigned v = 0;
        if (tid < NBUCK && tid >= off) v = scur[tid - off];
        __syncthreads();
        if (tid < NBUCK) scur[tid] += v;
        __syncthreads();
    }
    if (tid < NBUCK) {
        unsigned ex = scur[tid] - hist[tid];
        sofs[tid] = ex;
        scur[tid] = ex;
    }
    __syncthreads();
    // phase 3: scatter slab edges into LDS staging sorted by bucket
    for (int e = start + tid; e < end; e += 1024) {
        int s, d;
        if (mult == 2) { s = ((const int2*)idx)[e].x; d = ((const int2*)idx)[(size_t)E + e].x; }
        else           { s = idx[e];                  d = idx[(size_t)E + e]; }
        unsigned pos = atomicAdd(&scur[d >> NPB_SHIFT], 1u);
        stage[pos] = ((unsigned)(d & (NPB - 1)) << 17) | (unsigned)s;
    }
    __syncthreads();
    // phase 4: copy-out, one 16-lane group per bucket segment
    int g = tid >> 4, lane = tid & 15;       // 64 groups
    for (int b = g; b < NBUCK; b += 64) {
        unsigned s0 = sofs[b], len = scur[b] - s0;
        if (len == 0) continue;
        unsigned gbase = cnt[(size_t)b * NB + blockIdx.x] + bucketPtr[b];
        for (unsigned i = lane; i < len; i += 16)
            binned[gbase + i] = stage[s0 + i];
    }
}

// Fused per-bucket (1024 threads): degree histogram -> scan -> ptr + dinv,
// then sort the bucket's edges into LDS staging by node and stream out
// col[] as one coalesced sequential copy (fallback: direct scatter).
__global__ void __launch_bounds__(1024, 8)
k_ptrfill(const unsigned* __restrict__ bucketPtr,
          const unsigned* __restrict__ binned,
          unsigned* __restrict__ p0,
          float* __restrict__ dinv, int* __restrict__ col,
          int n, int E) {
    __shared__ unsigned deg[NPB];
    __shared__ unsigned cur[NPB];
    __shared__ unsigned sh[NPB];
    __shared__ unsigned stage[STAGE_CAP];   // 72 KB
    int tid = threadIdx.x, bb = blockIdx.x;
    if (tid < NPB) deg[tid] = 0;
    __syncthreads();
    unsigned start = bucketPtr[bb], end = bucketPtr[bb + 1];
    unsigned cntE = end - start;
    for (unsigned i = start + tid; i < end; i += 1024)
        atomicAdd(&deg[binned[i] >> 17], 1u);
    __syncthreads();
    unsigned d0 = 0;
    if (tid < NPB) { d0 = deg[tid]; sh[tid] = d0; }
    __syncthreads();
    for (int off = 1; off < NPB; off <<= 1) {
        unsigned v = 0;
        if (tid < NPB && tid >= off) v = sh[tid - off];
        __syncthreads();
        if (tid < NPB) sh[tid] += v;
        __syncthreads();
    }
    if (tid < NPB) {
        unsigned lbase = sh[tid] - d0;        // exclusive prefix (local)
        cur[tid] = lbase;
        int v = (bb << NPB_SHIFT) + tid;
        if (v < n) {
            p0[v] = start + lbase;
            dinv[v] = rsqrtf((float)(d0 + 1u));   // +1 self-loop
        }
    }
    if (bb == 0 && tid == 0) p0[n] = (unsigned)E;
    __syncthreads();
    if (cntE <= STAGE_CAP) {
        for (unsigned i = start + tid; i < end; i += 1024) {
            unsigned entry = binned[i];
            unsigned pos = atomicAdd(&cur[entry >> 17], 1u);
            stage[pos] = entry & 0x1FFFFu;
        }
        __syncthreads();
        for (unsigned i = tid; i < cntE; i += 1024)
            col[start + i] = (int)stage[i];
    } else {
        for (unsigned i = start + tid; i < end; i += 1024) {
            unsigned entry = binned[i];
            unsigned pos = atomicAdd(&cur[entry >> 17], 1u);
            col[start + pos] = (int)(entry & 0x1FFFFu);
        }
    }
}

// g1[v][j] = dinv[v] * (x[v] . W1[:,j]), stored as fp16 (gather table is
// then 3.2 MB -> fits one XCD's 4 MB L2). 16 nodes x 16 feats per block.
__global__ void k_gemm1(const float* __restrict__ x, const float* __restrict__ W1,
                        const float* __restrict__ dinv,
                        h16* __restrict__ g1, int n) {
    __shared__ float w1s[F_IN * F_HID];     // 8 KB
    __shared__ float xs[16][F_IN + 4];
    int tid = threadIdx.x;
    for (int i = tid; i < F_IN * F_HID; i += 256) w1s[i] = W1[i];
    int nb = blockIdx.x * 16;
    for (int q = tid; q < 512; q += 256) {
        int r = q >> 5, k4 = q & 31;
        int g = nb + r;
        float4 v = make_float4(0.f, 0.f, 0.f, 0.f);
        if (g < n) v = ((const float4*)x)[(size_t)g * 32 + k4];
        xs[r][k4 * 4 + 0] = v.x; xs[r][k4 * 4 + 1] = v.y;
        xs[r][k4 * 4 + 2] = v.z; xs[r][k4 * 4 + 3] = v.w;
    }
    __syncthreads();
    int r = tid >> 4, j = tid & 15;
    int g = nb + r;
    if (g < n) {
        float acc = 0.f;
#pragma unroll
        for (int k = 0; k < F_IN; ++k) acc += xs[r][k] * w1s[k * F_HID + j];
        g1[(size_t)g * F_HID + j] = (h16)(acc * dinv[g]);
    }
}

// Pull-mode CSR aggregation, full row range per node. fp16 gather table
// (32 B rows): 2 lanes per node, each gathering 16 B (h16x8); fp32
// accumulate. Table loads CACHED (L2-resident by design); col NT-streamed.
// Self-loop = init; fused epilogue writes fp16 (next stage's table).
template <int RELU>
__global__ void __launch_bounds__(256)
k_agg(const unsigned* __restrict__ p0, const int* __restrict__ col,
      const h16x8* __restrict__ gin8, h16x8* __restrict__ gout8,
      const float* __restrict__ dinv, const float* __restrict__ b1, int n) {
    int t = blockIdx.x * blockDim.x + threadIdx.x;
    int v = t >> 1, q = t & 1;            // q = 16B half of the 32B row
    if (v >= n) return;
    size_t o = (size_t)v * 2 + q;
    f32x8 acc = __builtin_convertvector(gin8[o], f32x8);   // self-loop
    unsigned i = p0[v], end = p0[v + 1];
    for (; i + 8 <= end; i += 8) {
        int u0 = __builtin_nontemporal_load(col + i);
        int u1 = __builtin_nontemporal_load(col + i + 1);
        int u2 = __builtin_nontemporal_load(col + i + 2);
        int u3 = __builtin_nontemporal_load(col + i + 3);
        int u4 = __builtin_nontemporal_load(col + i + 4);
        int u5 = __builtin_nontemporal_load(col + i + 5);
        int u6 = __builtin_nontemporal_load(col + i + 6);
        int u7 = __builtin_nontemporal_load(col + i + 7);
        h16x8 a0 = gin8[(size_t)u0 * 2 + q];
        h16x8 a1 = gin8[(size_t)u1 * 2 + q];
        h16x8 a2 = gin8[(size_t)u2 * 2 + q];
        h16x8 a3 = gin8[(size_t)u3 * 2 + q];
        h16x8 a4 = gin8[(size_t)u4 * 2 + q];
        h16x8 a5 = gin8[(size_t)u5 * 2 + q];
        h16x8 a6 = gin8[(size_t)u6 * 2 + q];
        h16x8 a7 = gin8[(size_t)u7 * 2 + q];
        f32x8 s01 = __builtin_convertvector(a0, f32x8) + __builtin_convertvector(a1, f32x8);
        f32x8 s23 = __builtin_convertvector(a2, f32x8) + __builtin_convertvector(a3, f32x8);
        f32x8 s45 = __builtin_convertvector(a4, f32x8) + __builtin_convertvector(a5, f32x8);
        f32x8 s67 = __builtin_convertvector(a6, f32x8) + __builtin_convertvector(a7, f32x8);
        acc += (s01 + s23) + (s45 + s67);
    }
    for (; i < end; ++i)
        acc += __builtin_convertvector(
            gin8[(size_t)__builtin_nontemporal_load(col + i) * 2 + q], f32x8);
    float di = dinv[v];
    f32x8 r;
    if (RELU) {
        const float* b = b1 + q * 8;
#pragma unroll
        for (int k = 0; k < 8; ++k) r[k] = fmaxf(di * acc[k] + b[k], 0.f) * di;
    } else {
        r = acc * di;
    }
    gout8[o] = __builtin_convertvector(r, h16x8);   // cached store: next pass reads it
}

// Node-tiled output GEMM: block owns OUT_NV contiguous nodes; fp16 B rows
// staged once in LDS as fp32, outputs written coalesced NT.
// out[v][c] = B[v] . W2[:,c] + b2[c]   (dinv already folded into B)
__global__ void __launch_bounds__(256)
k_out(const h16* __restrict__ B,
      const float* __restrict__ W2, const float* __restrict__ b2,
      float* __restrict__ out, int n) {
    __shared__ float w2s[F_HID * F_OUT];   // 8.8 KB
    __shared__ float b2s[F_OUT];
    __shared__ float Bs[OUT_NV][F_HID];    // 1 KB
    int tid = threadIdx.x;
    for (int i = tid; i < F_HID * F_OUT; i += 256) w2s[i] = W2[i];
    if (tid < F_OUT) b2s[tid] = b2[tid];
    int vbase = blockIdx.x * OUT_NV;
    {
        int vl = tid >> 4, j = tid & 15;
        int v = vbase + vl;
        Bs[vl][j] = (v < n) ? (float)B[(size_t)v * F_HID + j] : 0.f;
    }
    __syncthreads();
    const int total = OUT_NV * F_OUT;   // 2208
    for (int q = tid; q < total; q += 256) {
        int vl = q / F_OUT, c = q - vl * F_OUT;
        int v = vbase + vl;
        if (v >= n) continue;
        float acc = b2s[c];
#pragma unroll
        for (int j = 0; j < F_HID; ++j) acc += Bs[vl][j] * w2s[j * F_OUT + c];
        __builtin_nontemporal_store(acc, out + (size_t)v * F_OUT + c);
    }
}

extern "C" void kernel_launch(void* const* d_in, const int* in_sizes, int n_in,
                              void* d_out, int out_size, void* d_ws, size_t ws_size,
                              hipStream_t stream) {
    const float* x   = (const float*)d_in[0];
    const int*   idx = (const int*)d_in[1];
    const float* W1  = (const float*)d_in[2];
    const float* b1  = (const float*)d_in[3];
    const float* W2  = (const float*)d_in[4];
    const float* b2  = (const float*)d_in[5];
    float* out = (float*)d_out;

    const int n = in_sizes[0] / F_IN;       // 100000
    const int E = in_sizes[1] / 2;          // 6400000

    char* ws = (char*)d_ws;
    size_t off = 0;
    auto carve = [&](size_t bytes) { char* p = ws + off; off += (bytes + 255) / 256 * 256; return p; };
    float*    dinv      = (float*)carve((size_t)n * 4);
    unsigned* bucketPtr = (unsigned*)carve((NBUCK + 1) * 4);
    unsigned* bucketTot = (unsigned*)carve(NBUCK * 4);
    unsigned* cnt       = (unsigned*)carve((size_t)NBUCK * NB * 4);   // 1 MB
    unsigned* p0        = (unsigned*)carve(((size_t)n + 1) * 4);
    h16*      bufA      = (h16*)carve((size_t)n * F_HID * 2);         // 3.2 MB fp16
    h16*      bufB      = (h16*)carve((size_t)n * F_HID * 2);         // 3.2 MB fp16
    // binned (E words = 25.6 MB) and col (E words) live in d_out (55.2 MB);
    // both fully consumed before k_out overwrites d_out.
    unsigned* binned = (unsigned*)d_out;
    int*      col    = (int*)d_out + (size_t)E;

    const int B = 256;
    const int nbAgg2 = (n * 2 + B - 1) / B;   // 782
    k_bincount<<<NB, 1024, 0, stream>>>(idx, cnt, E);
    k_scanA   <<<NBUCK, B, 0, stream>>>(cnt, bucketTot);
    k_scanB   <<<1, NBUCK, 0, stream>>>(bucketTot, bucketPtr);
    k_binfill <<<NB, 1024, 0, stream>>>(idx, cnt, bucketPtr, binned, E);
    k_ptrfill <<<NBUCK, 1024, 0, stream>>>(bucketPtr, binned, p0, dinv, col, n, E);
    k_gemm1   <<<(n + 15) / 16, B, 0, stream>>>(x, W1, dinv, bufA, n);
    // layer 1 (full-range pass, fused relu epilogue)
    k_agg<1>  <<<nbAgg2, B, 0, stream>>>(p0, col, (const h16x8*)bufA,
                                         (h16x8*)bufB, dinv, b1, n);
    // layer 2
    k_agg<0>  <<<nbAgg2, B, 0, stream>>>(p0, col, (const h16x8*)bufB,
                                         (h16x8*)bufA, dinv, b1, n);
    k_out     <<<(n + OUT_NV - 1) / OUT_NV, B, 0, stream>>>(bufA, W2, b2, out, n);
}

// Round 17
// 223.636 us; speedup vs baseline: 1.6989x; 1.1106x over previous
//
#include <hip/hip_runtime.h>
#include <cstdint>

#define F_IN  128
#define F_HID 16
#define F_OUT 138
#define NBUCK 512        // dst buckets
#define NPB_SHIFT 8
#define NPB 256          // nodes per bucket
#define NB  512          // edge slabs for binning passes
#define SLAB_CAP 12544   // >= ceil(E/NB) = 12500
#define STAGE_CAP 18432  // >= max bucket edges (~16.4k avg + slack)
#define OUT_NV 16        // nodes per k_out block

typedef float f32x8 __attribute__((ext_vector_type(8)));
typedef _Float16 h16;
typedef _Float16 h16x8 __attribute__((ext_vector_type(8)));   // 16 B

// ---------------------------------------------------------------------------
// Inline edge_index dtype detection: int64 (LE, values < 2^31) -> every odd
// int32 word is zero. Returns 2 (int64 stride in words) or 1 (int32).
__device__ __forceinline__ int edge_mult(const int* __restrict__ idx) {
    int nz = 0;
#pragma unroll
    for (int i = 1; i < 64; i += 2) nz |= idx[i];
    return nz ? 1 : 2;
}

// Pass A: per-slab LDS histogram of dst-buckets (reads dst only).
__global__ void __launch_bounds__(1024, 8)
k_bincount(const int* __restrict__ idx, unsigned* __restrict__ cnt, int E) {
    __shared__ unsigned hist[NBUCK];
    int tid = threadIdx.x;
    if (tid < NBUCK) hist[tid] = 0;
    __syncthreads();
    const int mult = edge_mult(idx);
    int slab = (E + NB - 1) / NB;
    int start = blockIdx.x * slab, end = min(E, start + slab);
    if (mult == 2) {
        for (int e = start + tid; e < end; e += 1024)
            atomicAdd(&hist[((const int2*)idx)[(size_t)E + e].x >> NPB_SHIFT], 1u);
    } else {
        for (int e = start + tid; e < end; e += 1024)
            atomicAdd(&hist[idx[(size_t)E + e] >> NPB_SHIFT], 1u);
    }
    __syncthreads();
    if (tid < NBUCK) cnt[(size_t)tid * NB + blockIdx.x] = hist[tid];
}

// Scan step 1: one block per bucket; exclusive-scan its NB slab counts in
// place (pair-per-thread Hillis-Steele); emit bucket total.
__global__ void k_scanA(unsigned* __restrict__ cnt, unsigned* __restrict__ bucketTot) {
    __shared__ unsigned sh[256];
    int t = threadIdx.x;
    unsigned* row = cnt + (size_t)blockIdx.x * NB;
    unsigned e0 = row[2 * t], e1 = row[2 * t + 1];
    unsigned pair = e0 + e1;
    sh[t] = pair;
    __syncthreads();
    for (int off = 1; off < 256; off <<= 1) {
        unsigned v = (t >= off) ? sh[t - off] : 0u;
        __syncthreads();
        sh[t] += v;
        __syncthreads();
    }
    unsigned excl = sh[t] - pair;
    row[2 * t] = excl;
    row[2 * t + 1] = excl + e0;
    if (t == 255) bucketTot[blockIdx.x] = sh[255];
}

// Scan step 2: one block (512 threads); exclusive scan of bucket totals.
__global__ void k_scanB(const unsigned* __restrict__ bucketTot,
                        unsigned* __restrict__ bucketPtr) {
    __shared__ unsigned sh[NBUCK];
    int t = threadIdx.x;
    unsigned c = bucketTot[t];
    sh[t] = c;
    __syncthreads();
    for (int off = 1; off < NBUCK; off <<= 1) {
        unsigned v = (t >= off) ? sh[t - off] : 0u;
        __syncthreads();
        sh[t] += v;
        __syncthreads();
    }
    bucketPtr[t] = sh[t] - c;          // exclusive
    if (t == NBUCK - 1) bucketPtr[NBUCK] = sh[t];
}

// Pass B with LDS write-combining, 1024 threads: histogram slab by bucket,
// scan, scatter the slab's edges into LDS staging sorted by bucket, then
// 16-lane-group copy-out to each (slab,bucket) global segment (~24 entries).
// Packed entry: (dstLocal<<17) | src  (8+17 = 25 bits, src < 2^17).
__global__ void __launch_bounds__(1024, 8)
k_binfill(const int* __restrict__ idx,
          const unsigned* __restrict__ cnt,
          const unsigned* __restrict__ bucketPtr,
          unsigned* __restrict__ binned, int E) {
    __shared__ unsigned hist[NBUCK];
    __shared__ unsigned sofs[NBUCK];
    __shared__ unsigned scur[NBUCK];
    __shared__ unsigned stage[SLAB_CAP];   // 50 KB
    int tid = threadIdx.x;
    if (tid < NBUCK) hist[tid] = 0;
    __syncthreads();
    const int mult = edge_mult(idx);
    int slab = (E + NB - 1) / NB;
    int start = blockIdx.x * slab, end = min(E, start + slab);
    // phase 1: histogram (dst only)
    if (mult == 2) {
        for (int e = start + tid; e < end; e += 1024)
            atomicAdd(&hist[((const int2*)idx)[(size_t)E + e].x >> NPB_SHIFT], 1u);
    } else {
        for (int e = start + tid; e < end; e += 1024)
            atomicAdd(&hist[idx[(size_t)E + e] >> NPB_SHIFT], 1u);
    }
    __syncthreads();
    // phase 2: exclusive scan of NBUCK counts (Hillis-Steele on tid<NBUCK)
    if (tid < NBUCK) scur[tid] = hist[tid];
    __syncthreads();
    for (int off = 1; off < NBUCK; off <<= 1) {
        unsigned v = 0;
        if (tid < NBUCK && tid >= off) v = scur[tid - off];
        __syncthreads();
        if (tid < NBUCK) scur[tid] += v;
        __syncthreads();
    }
    if (tid < NBUCK) {
        unsigned ex = scur[tid] - hist[tid];
        sofs[tid] = ex;
        scur[tid] = ex;
    }
    __syncthreads();
    // phase 3: scatter slab edges into LDS staging sorted by bucket
    for (int e = start + tid; e < end; e += 1024) {
        int s, d;
        if (mult == 2) { s = ((const int2*)idx)[e].x; d = ((const int2*)idx)[(size_t)E + e].x; }
        else           { s = idx[e];                  d = idx[(size_t)E + e]; }
        unsigned pos = atomicAdd(&scur[d >> NPB_SHIFT], 1u);
        stage[pos] = ((unsigned)(d & (NPB - 1)) << 17) | (unsigned)s;
    }
    __syncthreads();
    // phase 4: copy-out, one 16-lane group per bucket segment
    int g = tid >> 4, lane = tid & 15;       // 64 groups
    for (int b = g; b < NBUCK; b += 64) {
        unsigned s0 = sofs[b], len = scur[b] - s0;
        if (len == 0) continue;
        unsigned gbase = cnt[(size_t)b * NB + blockIdx.x] + bucketPtr[b];
        for (unsigned i = lane; i < len; i += 16)
            binned[gbase + i] = stage[s0 + i];
    }
}

// Fused per-bucket (1024 threads): degree histogram -> scan -> ptr + dinv,
// then sort the bucket's edges into LDS staging by node and stream out
// col[] as one coalesced sequential copy (fallback: direct scatter).
__global__ void __launch_bounds__(1024, 8)
k_ptrfill(const unsigned* __restrict__ bucketPtr,
          const unsigned* __restrict__ binned,
          unsigned* __restrict__ p0,
          float* __restrict__ dinv, int* __restrict__ col,
          int n, int E) {
    __shared__ unsigned deg[NPB];
    __shared__ unsigned cur[NPB];
    __shared__ unsigned sh[NPB];
    __shared__ unsigned stage[STAGE_CAP];   // 72 KB
    int tid = threadIdx.x, bb = blockIdx.x;
    if (tid < NPB) deg[tid] = 0;
    __syncthreads();
    unsigned start = bucketPtr[bb], end = bucketPtr[bb + 1];
    unsigned cntE = end - start;
    for (unsigned i = start + tid; i < end; i += 1024)
        atomicAdd(&deg[binned[i] >> 17], 1u);
    __syncthreads();
    unsigned d0 = 0;
    if (tid < NPB) { d0 = deg[tid]; sh[tid] = d0; }
    __syncthreads();
    for (int off = 1; off < NPB; off <<= 1) {
        unsigned v = 0;
        if (tid < NPB && tid >= off) v = sh[tid - off];
        __syncthreads();
        if (tid < NPB) sh[tid] += v;
        __syncthreads();
    }
    if (tid < NPB) {
        unsigned lbase = sh[tid] - d0;        // exclusive prefix (local)
        cur[tid] = lbase;
        int v = (bb << NPB_SHIFT) + tid;
        if (v < n) {
            p0[v] = start + lbase;
            dinv[v] = rsqrtf((float)(d0 + 1u));   // +1 self-loop
        }
    }
    if (bb == 0 && tid == 0) p0[n] = (unsigned)E;
    __syncthreads();
    if (cntE <= STAGE_CAP) {
        for (unsigned i = start + tid; i < end; i += 1024) {
            unsigned entry = binned[i];
            unsigned pos = atomicAdd(&cur[entry >> 17], 1u);
            stage[pos] = entry & 0x1FFFFu;
        }
        __syncthreads();
        for (unsigned i = tid; i < cntE; i += 1024)
            col[start + i] = (int)stage[i];
    } else {
        for (unsigned i = start + tid; i < end; i += 1024) {
            unsigned entry = binned[i];
            unsigned pos = atomicAdd(&cur[entry >> 17], 1u);
            col[start + pos] = (int)(entry & 0x1FFFFu);
        }
    }
}

// g1[v][j] = dinv[v] * (x[v] . W1[:,j]), stored as fp16 (gather table is
// then 3.2 MB -> fits one XCD's 4 MB L2). 16 nodes x 16 feats per block.
__global__ void k_gemm1(const float* __restrict__ x, const float* __restrict__ W1,
                        const float* __restrict__ dinv,
                        h16* __restrict__ g1, int n) {
    __shared__ float w1s[F_IN * F_HID];     // 8 KB
    __shared__ float xs[16][F_IN + 4];
    int tid = threadIdx.x;
    for (int i = tid; i < F_IN * F_HID; i += 256) w1s[i] = W1[i];
    int nb = blockIdx.x * 16;
    for (int q = tid; q < 512; q += 256) {
        int r = q >> 5, k4 = q & 31;
        int g = nb + r;
        float4 v = make_float4(0.f, 0.f, 0.f, 0.f);
        if (g < n) v = ((const float4*)x)[(size_t)g * 32 + k4];
        xs[r][k4 * 4 + 0] = v.x; xs[r][k4 * 4 + 1] = v.y;
        xs[r][k4 * 4 + 2] = v.z; xs[r][k4 * 4 + 3] = v.w;
    }
    __syncthreads();
    int r = tid >> 4, j = tid & 15;
    int g = nb + r;
    if (g < n) {
        float acc = 0.f;
#pragma unroll
        for (int k = 0; k < F_IN; ++k) acc += xs[r][k] * w1s[k * F_HID + j];
        g1[(size_t)g * F_HID + j] = (h16)(acc * dinv[g]);
    }
}

// Pull-mode CSR aggregation, 8 threads/node: (sub=0..3) x (q=0..1).
// Each thread gathers a contiguous QUARTER of the node's edge range (h16x8
// 16 B loads, fp32 accumulate), then 2-step __shfl_xor (masks 2,4) combines
// the four partials. sub==0 adds the self-loop, applies the epilogue, and
// stores fp16. 4x the waves of the 2-lane version -> latency hidden.
template <int RELU>
__global__ void __launch_bounds__(256)
k_agg(const unsigned* __restrict__ p0, const int* __restrict__ col,
      const h16x8* __restrict__ gin8, h16x8* __restrict__ gout8,
      const float* __restrict__ dinv, const float* __restrict__ b1, int n) {
    int t = blockIdx.x * blockDim.x + threadIdx.x;
    int v = t >> 3;
    int sub = (t >> 1) & 3;
    int q = t & 1;
    if (v >= n) return;
    unsigned rs = p0[v], re = p0[v + 1];
    unsigned deg = re - rs;
    unsigned chunk = (deg + 3) >> 2;
    unsigned cs = rs + sub * chunk;
    unsigned ce = min(re, cs + chunk);
    f32x8 acc = (f32x8)0.f;
    unsigned i = cs;
    for (; i + 8 <= ce; i += 8) {
        int u0 = __builtin_nontemporal_load(col + i);
        int u1 = __builtin_nontemporal_load(col + i + 1);
        int u2 = __builtin_nontemporal_load(col + i + 2);
        int u3 = __builtin_nontemporal_load(col + i + 3);
        int u4 = __builtin_nontemporal_load(col + i + 4);
        int u5 = __builtin_nontemporal_load(col + i + 5);
        int u6 = __builtin_nontemporal_load(col + i + 6);
        int u7 = __builtin_nontemporal_load(col + i + 7);
        h16x8 a0 = gin8[(size_t)u0 * 2 + q];
        h16x8 a1 = gin8[(size_t)u1 * 2 + q];
        h16x8 a2 = gin8[(size_t)u2 * 2 + q];
        h16x8 a3 = gin8[(size_t)u3 * 2 + q];
        h16x8 a4 = gin8[(size_t)u4 * 2 + q];
        h16x8 a5 = gin8[(size_t)u5 * 2 + q];
        h16x8 a6 = gin8[(size_t)u6 * 2 + q];
        h16x8 a7 = gin8[(size_t)u7 * 2 + q];
        f32x8 s01 = __builtin_convertvector(a0, f32x8) + __builtin_convertvector(a1, f32x8);
        f32x8 s23 = __builtin_convertvector(a2, f32x8) + __builtin_convertvector(a3, f32x8);
        f32x8 s45 = __builtin_convertvector(a4, f32x8) + __builtin_convertvector(a5, f32x8);
        f32x8 s67 = __builtin_convertvector(a6, f32x8) + __builtin_convertvector(a7, f32x8);
        acc += (s01 + s23) + (s45 + s67);
    }
    for (; i < ce; ++i)
        acc += __builtin_convertvector(
            gin8[(size_t)__builtin_nontemporal_load(col + i) * 2 + q], f32x8);
    // combine the 4 sub-partials (lane bits 1,2 within the 8-lane node group)
#pragma unroll
    for (int k = 0; k < 8; ++k) acc[k] += __shfl_xor((float)acc[k], 2);
#pragma unroll
    for (int k = 0; k < 8; ++k) acc[k] += __shfl_xor((float)acc[k], 4);
    if (sub == 0) {
        size_t o = (size_t)v * 2 + q;
        acc += __builtin_convertvector(gin8[o], f32x8);   // self-loop
        float di = dinv[v];
        f32x8 r;
        if (RELU) {
            const float* b = b1 + q * 8;
#pragma unroll
            for (int k = 0; k < 8; ++k) r[k] = fmaxf(di * acc[k] + b[k], 0.f) * di;
        } else {
            r = acc * di;
        }
        gout8[o] = __builtin_convertvector(r, h16x8);   // cached: next pass reads it
    }
}

// Node-tiled output GEMM: block owns OUT_NV contiguous nodes; fp16 B rows
// staged once in LDS as fp32, outputs written coalesced NT.
// out[v][c] = B[v] . W2[:,c] + b2[c]   (dinv already folded into B)
__global__ void __launch_bounds__(256)
k_out(const h16* __restrict__ B,
      const float* __restrict__ W2, const float* __restrict__ b2,
      float* __restrict__ out, int n) {
    __shared__ float w2s[F_HID * F_OUT];   // 8.8 KB
    __shared__ float b2s[F_OUT];
    __shared__ float Bs[OUT_NV][F_HID];    // 1 KB
    int tid = threadIdx.x;
    for (int i = tid; i < F_HID * F_OUT; i += 256) w2s[i] = W2[i];
    if (tid < F_OUT) b2s[tid] = b2[tid];
    int vbase = blockIdx.x * OUT_NV;
    {
        int vl = tid >> 4, j = tid & 15;
        int v = vbase + vl;
        Bs[vl][j] = (v < n) ? (float)B[(size_t)v * F_HID + j] : 0.f;
    }
    __syncthreads();
    const int total = OUT_NV * F_OUT;   // 2208
    for (int q = tid; q < total; q += 256) {
        int vl = q / F_OUT, c = q - vl * F_OUT;
        int v = vbase + vl;
        if (v >= n) continue;
        float acc = b2s[c];
#pragma unroll
        for (int j = 0; j < F_HID; ++j) acc += Bs[vl][j] * w2s[j * F_OUT + c];
        __builtin_nontemporal_store(acc, out + (size_t)v * F_OUT + c);
    }
}

extern "C" void kernel_launch(void* const* d_in, const int* in_sizes, int n_in,
                              void* d_out, int out_size, void* d_ws, size_t ws_size,
                              hipStream_t stream) {
    const float* x   = (const float*)d_in[0];
    const int*   idx = (const int*)d_in[1];
    const float* W1  = (const float*)d_in[2];
    const float* b1  = (const float*)d_in[3];
    const float* W2  = (const float*)d_in[4];
    const float* b2  = (const float*)d_in[5];
    float* out = (float*)d_out;

    const int n = in_sizes[0] / F_IN;       // 100000
    const int E = in_sizes[1] / 2;          // 6400000

    char* ws = (char*)d_ws;
    size_t off = 0;
    auto carve = [&](size_t bytes) { char* p = ws + off; off += (bytes + 255) / 256 * 256; return p; };
    float*    dinv      = (float*)carve((size_t)n * 4);
    unsigned* bucketPtr = (unsigned*)carve((NBUCK + 1) * 4);
    unsigned* bucketTot = (unsigned*)carve(NBUCK * 4);
    unsigned* cnt       = (unsigned*)carve((size_t)NBUCK * NB * 4);   // 1 MB
    unsigned* p0        = (unsigned*)carve(((size_t)n + 1) * 4);
    h16*      bufA      = (h16*)carve((size_t)n * F_HID * 2);         // 3.2 MB fp16
    h16*      bufB      = (h16*)carve((size_t)n * F_HID * 2);         // 3.2 MB fp16
    // binned (E words = 25.6 MB) and col (E words) live in d_out (55.2 MB);
    // both fully consumed before k_out overwrites d_out.
    unsigned* binned = (unsigned*)d_out;
    int*      col    = (int*)d_out + (size_t)E;

    const int B = 256;
    const int nbAgg8 = (n * 8 + B - 1) / B;   // 3125
    k_bincount<<<NB, 1024, 0, stream>>>(idx, cnt, E);
    k_scanA   <<<NBUCK, B, 0, stream>>>(cnt, bucketTot);
    k_scanB   <<<1, NBUCK, 0, stream>>>(bucketTot, bucketPtr);
    k_binfill <<<NB, 1024, 0, stream>>>(idx, cnt, bucketPtr, binned, E);
    k_ptrfill <<<NBUCK, 1024, 0, stream>>>(bucketPtr, binned, p0, dinv, col, n, E);
    k_gemm1   <<<(n + 15) / 16, B, 0, stream>>>(x, W1, dinv, bufA, n);
    // layer 1 (edge-split pass, fused relu epilogue)
    k_agg<1>  <<<nbAgg8, B, 0, stream>>>(p0, col, (const h16x8*)bufA,
                                         (h16x8*)bufB, dinv, b1, n);
    // layer 2
    k_agg<0>  <<<nbAgg8, B, 0, stream>>>(p0, col, (const h16x8*)bufB,
                                         (h16x8*)bufA, dinv, b1, n);
    k_out     <<<(n + OUT_NV - 1) / OUT_NV, B, 0, stream>>>(bufA, W2, b2, out, n);
}